// Round 9
// baseline (374.047 us; speedup 1.0000x reference)
//
#include <hip/hip_runtime.h>
#include <math.h>

// ViT encoder block (DeepViT ReAttention), B=4 N=1024 D=768 H=8 hd=96 Hdim=3072
// R9: attn2 epilogue fix — U partials staged through LDS and written as full
// cachelines (kills write-allocate RMW traffic: WRITE 92->~55MB, FETCH 79->~45MB)
// + invZ preloaded per thread (removes per-unit serial L2 load).

typedef unsigned short u16;
typedef unsigned int u32;
typedef __bf16 bf16x8 __attribute__((ext_vector_type(8)));
typedef float f32x4 __attribute__((ext_vector_type(4)));

#define EPSV 1e-5f
#define SL2E 0.14724444620253177f   // 96^-0.5 * log2(e), folded into q at conv
#define EXPC -11.541560327111707f   // -8 * log2(e)

__device__ __forceinline__ u16 f2bf(float f) {
  union { float f; u32 u; } v; v.f = f;
  u32 u = v.u + 0x7fffu + ((v.u >> 16) & 1u);
  return (u16)(u >> 16);
}
__device__ __forceinline__ float bf2f(u16 h) {
  union { u32 u; float f; } v; v.u = ((u32)h) << 16; return v.f;
}
__device__ __forceinline__ f32x4 mfma16(bf16x8 a, bf16x8 b, f32x4 c) {
  return __builtin_amdgcn_mfma_f32_16x16x32_bf16(a, b, c, 0, 0, 0);
}
__device__ __forceinline__ void gload16(const void* gp, void* lp) {
  __builtin_amdgcn_global_load_lds(
      (const __attribute__((address_space(1))) u32*)gp,
      (__attribute__((address_space(3))) u32*)lp, 16, 0, 0);
}

// ---- K staging: LINEAR LDS dest (granule G = j*512 + w*64 + lane), source
// address carries the layout permutation (inverse of the frag-native map).
struct KS { int off[3]; int hl[3]; };
__device__ __forceinline__ KS ks_init(int t) {
  KS ks;
  int lane = t & 63;
  int lh = lane >> 4, l15 = lane & 15;
  #pragma unroll
  for (int j = 0; j < 3; ++j) {
    int G = j * 512 + t;                 // granule in [0,1536)
    int hl = (G >= 768) ? 1 : 0;         // 0 = khi half, 1 = klo half
    int C = (G - hl * 768) >> 6;         // uniform per (j,wave)
    int chunk = C / 6, r = C - 6 * chunk;
    int kk = r >> 1, c1 = r & 1;
    int m = chunk * 32 + ((l15 >> 2) << 3) + (c1 << 2) + (l15 & 3);
    ks.off[j] = m * 96 + kk * 32 + lh * 8;
    ks.hl[j] = hl;
  }
  return ks;
}
__device__ __forceinline__ void ks_stage(const u16* __restrict__ khi,
    const u16* __restrict__ klo, size_t rowel, const KS& ks, u16* Kb, int t) {
  int w = t >> 6;
  #pragma unroll
  for (int j = 0; j < 3; ++j) {
    const u16* src = (ks.hl[j] ? klo : khi) + rowel + ks.off[j];
    gload16(src, Kb + (size_t)(j * 512 + w * 64) * 8);
  }
}

__device__ __forceinline__ void qload(const u16* __restrict__ qhi,
    const u16* __restrict__ qlo, size_t qoff, bf16x8* qh, bf16x8* ql) {
  #pragma unroll
  for (int kk = 0; kk < 3; ++kk) {
    qh[kk] = *(const bf16x8*)(qhi + qoff + kk * 32);
    ql[kk] = *(const bf16x8*)(qlo + qoff + kk * 32);
  }
}

// 18-MFMA split-bf16 score pair for one 32m chunk (mh) from staged LDS K.
__device__ __forceinline__ void score18(const u16* Kb, int mh, int lane,
    const bf16x8* qh, const bf16x8* ql, f32x4& C0, f32x4& C1) {
  C0 = (f32x4){0.f, 0.f, 0.f, 0.f};
  C1 = (f32x4){0.f, 0.f, 0.f, 0.f};
  #pragma unroll
  for (int kk = 0; kk < 3; ++kk) {
    const u16* base = Kb + (mh * 6 + kk * 2) * 512 + lane * 8;
    bf16x8 kh0 = *(const bf16x8*)(base);
    bf16x8 kh1 = *(const bf16x8*)(base + 512);
    bf16x8 kl0 = *(const bf16x8*)(base + 6144);
    bf16x8 kl1 = *(const bf16x8*)(base + 6656);
    C0 = mfma16(kh0, qh[kk], C0);
    C0 = mfma16(kl0, qh[kk], C0);
    C0 = mfma16(kh0, ql[kk], C0);
    C1 = mfma16(kh1, qh[kk], C1);
    C1 = mfma16(kl1, qh[kk], C1);
    C1 = mfma16(kh1, ql[kk], C1);
  }
}

// ---------------------------------------------------------------- fp32 -> bf16
__global__ __launch_bounds__(256) void k_f2b(const float* __restrict__ s,
                                             u16* __restrict__ d, int n) {
  int i = blockIdx.x * 256 + threadIdx.x;
  int stride = gridDim.x * 256;
  for (; i < n; i += stride) d[i] = f2bf(s[i]);
}

// ---------------------------------------------------------------- conv 3x3 QKV
__global__ __launch_bounds__(256) void k_conv(const float* __restrict__ x,
    const float* __restrict__ wq, const float* __restrict__ wk, const float* __restrict__ wv,
    u16* __restrict__ qhi, u16* __restrict__ qlo,
    u16* __restrict__ khi, u16* __restrict__ klo,
    float* __restrict__ vb)
{
  __shared__ float patch[768], swq[81], swk[81], swv[81];
  int bid = blockIdx.x;            // b*1024 + n
  int b = bid >> 10, n = bid & 1023;
  int t = threadIdx.x;
  const float* xr = x + (size_t)bid * 768;
  patch[t] = xr[t]; patch[t + 256] = xr[t + 256]; patch[t + 512] = xr[t + 512];
  if (t < 81) { swq[t] = wq[t]; swk[t] = wk[t]; swv[t] = wv[t]; }
  __syncthreads();
  #pragma unroll
  for (int r = 0; r < 3; ++r) {
    int f = t + 256 * r;                       // c*256 + p*16 + q
    int o = f >> 8, rem = f & 255, pp = rem >> 4, qq = rem & 15;
    float aq = 0.f, ak = 0.f, av = 0.f;
    #pragma unroll
    for (int i = 0; i < 3; ++i)
      #pragma unroll
      for (int dp = 0; dp < 3; ++dp) {
        int ip = pp + dp - 1;
        if (ip < 0 || ip > 15) continue;
        #pragma unroll
        for (int dq = 0; dq < 3; ++dq) {
          int iq = qq + dq - 1;
          if (iq < 0 || iq > 15) continue;
          float pv = patch[i * 256 + ip * 16 + iq];
          int wi = ((o * 3 + i) * 3 + dp) * 3 + dq;
          aq += swq[wi] * pv; ak += swk[wi] * pv; av += swv[wi] * pv;
        }
      }
    int h = f / 96, d = f - h * 96;
    size_t oi = ((size_t)(b * 8 + h) * 1024 + n) * 96 + d;
    float aqs = aq * SL2E;           // fold softmax scale + log2e into q
    u16 qh_ = f2bf(aqs); qhi[oi] = qh_; qlo[oi] = f2bf(aqs - bf2f(qh_));
    u16 kh_ = f2bf(ak);  khi[oi] = kh_; klo[oi] = f2bf(ak - bf2f(kh_));
    vb[oi] = av;
  }
}

// ------------------------------- V transpose: [bh][n][d] f32 -> [bh][d][n] bf16
__global__ __launch_bounds__(256) void k_vtr(const float* __restrict__ vb,
                                             u16* __restrict__ vtr)
{
  __shared__ u16 lds[12288];     // [96 d][128 n]
  int bid = blockIdx.x;          // bh*8 + ntile
  int bh = bid >> 3, n0 = (bid & 7) * 128;
  int t = threadIdx.x;
  int n = t >> 1, dh = (t & 1) * 48;
  const float* src = vb + ((size_t)bh * 1024 + n0 + n) * 96 + dh;
  #pragma unroll
  for (int j4 = 0; j4 < 12; ++j4) {
    float4 v = *(const float4*)(src + j4 * 4);
    int d = dh + j4 * 4;
    lds[(d + 0) * 128 + n] = f2bf(v.x);
    lds[(d + 1) * 128 + n] = f2bf(v.y);
    lds[(d + 2) * 128 + n] = f2bf(v.z);
    lds[(d + 3) * 128 + n] = f2bf(v.w);
  }
  __syncthreads();
  #pragma unroll
  for (int j = 0; j < 48; ++j) {
    int flat = t + 256 * j;
    int d = flat >> 7, n2 = flat & 127;
    vtr[((size_t)bh * 96 + d) * 1024 + n0 + n2] = lds[flat];
  }
}

// ---------------- z-pass: zp[bh][slot16][n] = sum_m exp2(C+EXPC) over 64m slabs
__global__ __launch_bounds__(512, 4) void k_zpass(
    const u16* __restrict__ qhi, const u16* __restrict__ qlo,
    const u16* __restrict__ khi, const u16* __restrict__ klo,
    float* __restrict__ zp)
{
  __shared__ u16 Kst[2][12288];
  int p = blockIdx.x;            // 512 blocks
  int s = p >> 3;                // [0,64)
  int c = (p & 7) * 4 + (s >> 4);// [0,32) = (b,mg) combo
  int ng = s & 15;
  int b = c >> 3, mg = c & 7;
  int t = threadIdx.x, lane = t & 63, w = t >> 6;
  int l15 = lane & 15, lhi = lane >> 4;
  int nsub = w >> 1, mh = w & 1;
  int n0 = ng * 64 + nsub * 16;
  int m0base = mg * 128;
  KS ks = ks_init(t);
  bf16x8 qh[3], ql[3], qh2[3], ql2[3];
  size_t bh0 = (size_t)(b * 8) * 1024;
  ks_stage(khi, klo, (bh0 + m0base) * 96, ks, Kst[0], t);
  qload(qhi, qlo, (bh0 + n0 + l15) * 96 + lhi * 8, qh, ql);
  __syncthreads();
  #pragma unroll 1
  for (int h = 0; h < 8; ++h) {
    float z = 0.f;
    #pragma unroll
    for (int mt = 0; mt < 2; ++mt) {
      int u = h * 2 + mt;
      if (u < 15) {   // prefetch next unit into the free buffer
        int un = u + 1, hn = un >> 1, mtn = un & 1;
        size_t bhn = (size_t)(b * 8 + hn) * 1024;
        ks_stage(khi, klo, (bhn + m0base + mtn * 64) * 96, ks, Kst[(u + 1) & 1], t);
        if (mtn == 0)
          qload(qhi, qlo, (bhn + n0 + l15) * 96 + lhi * 8, qh2, ql2);
      }
      f32x4 C0, C1;
      score18(Kst[u & 1], mh, lane, qh, ql, C0, C1);
      #pragma unroll
      for (int r = 0; r < 4; ++r)
        z += exp2f(C0[r] + EXPC) + exp2f(C1[r] + EXPC);
      if (u < 15 && mt == 1) {
        #pragma unroll
        for (int kk = 0; kk < 3; ++kk) { qh[kk] = qh2[kk]; ql[kk] = ql2[kk]; }
      }
      __syncthreads();
    }
    z += __shfl_xor(z, 16);
    z += __shfl_xor(z, 32);
    if (lane < 16)
      zp[((size_t)((b * 8 + h) * 16 + mg * 2 + mh)) * 1024 + n0 + lane] = z;
  }
}

// --------------------------------------- merge 16 z slots -> invZ
__global__ __launch_bounds__(256) void k_zmerge(const float* __restrict__ zp,
                                                float* __restrict__ invZ)
{
  int idx = blockIdx.x * 256 + threadIdx.x;   // < 32768
  int bh = idx >> 10, n = idx & 1023;
  float z = 0.f;
  #pragma unroll
  for (int s = 0; s < 16; ++s) z += zp[((size_t)(bh * 16 + s)) * 1024 + n];
  invZ[idx] = 1.f / z;
}

// ---------------- fused attention: per block (b, 64n, 256m quarter).
__global__ __launch_bounds__(512, 2) void k_attn2(
    const u16* __restrict__ qhi, const u16* __restrict__ qlo,
    const u16* __restrict__ khi, const u16* __restrict__ klo,
    const u16* __restrict__ vtr, const float* __restrict__ invZ,
    const float* __restrict__ rw,
    float* __restrict__ U0, float* __restrict__ U1,
    float* __restrict__ U2, float* __restrict__ U3,
    float* __restrict__ pstat)
{
  __shared__ u16 Kst[2][12288];
  __shared__ u16 Plds[32768];    // [h 8][slot 8][lane 64][8 u16]; reused as U stage
  int p = blockIdx.x;            // 256 blocks
  int s = p >> 3;                // [0,32)
  int c = (p & 7) * 2 + (s >> 4);// [0,16) = (b,mq) combo
  int ng = s & 15;
  int b = c >> 2, mq = c & 3;
  int t = threadIdx.x, lane = t & 63, w = t >> 6;
  int l15 = lane & 15, lhi = lane >> 4;
  int nsub = w >> 1, mh = w & 1;   // head-phase role
  int n0 = ng * 64 + nsub * 16;
  int m0q = mq * 256;
  KS ks = ks_init(t);

  float wg[8]; float wsum = 0.f;
  #pragma unroll
  for (int h = 0; h < 8; ++h) { wg[h] = rw[w * 8 + h]; wsum += wg[h]; }
  float cg = -wsum * (1.f / 1024.f);
  float iz8[8];
  #pragma unroll
  for (int h = 0; h < 8; ++h) iz8[h] = invZ[(b * 8 + h) * 1024 + n0 + l15];
  f32x4 acc[4][6];
  #pragma unroll
  for (int i = 0; i < 4; ++i)
    #pragma unroll
    for (int ds = 0; ds < 6; ++ds) acc[i][ds] = (f32x4){0.f, 0.f, 0.f, 0.f};
  float sc = 0.f, scc = 0.f;
  size_t vbase = (size_t)(b * 8 + w) * 96;

  bf16x8 qh[3], ql[3], qh2[3], ql2[3];
  size_t bh0 = (size_t)(b * 8) * 1024;
  ks_stage(khi, klo, (bh0 + m0q) * 96, ks, Kst[0], t);
  qload(qhi, qlo, (bh0 + n0 + l15) * 96 + lhi * 8, qh, ql);
  __syncthreads();

  #pragma unroll 1
  for (int mt = 0; mt < 4; ++mt) {
    int m0 = m0q + mt * 64;
    #pragma unroll 1
    for (int h = 0; h < 8; ++h) {
      int u = mt * 8 + h;
      if (u < 31) {   // prefetch next unit into the free buffer
        int hn = (h + 1) & 7;
        int mtn = mt + (h == 7 ? 1 : 0);
        size_t bhn = (size_t)(b * 8 + hn) * 1024;
        ks_stage(khi, klo, (bhn + m0q + mtn * 64) * 96, ks, Kst[(u + 1) & 1], t);
        qload(qhi, qlo, (bhn + n0 + l15) * 96 + lhi * 8, qh2, ql2);
      }
      f32x4 C0, C1;
      score18(Kst[u & 1], mh, lane, qh, ql, C0, C1);
      float iz = iz8[h];
      union { u16 us[8]; bf16x8 bv; } pk;
      #pragma unroll
      for (int r = 0; r < 4; ++r) {
        pk.us[r]     = f2bf(exp2f(C0[r] + EXPC) * iz);
        pk.us[4 + r] = f2bf(exp2f(C1[r] + EXPC) * iz);
      }
      *(bf16x8*)&Plds[((h * 8 + w) * 64 + lane) * 8] = pk.bv;
      if (u < 31) {
        #pragma unroll
        for (int kk = 0; kk < 3; ++kk) { qh[kk] = qh2[kk]; ql[kk] = ql2[kk]; }
      }
      if (h < 7) __syncthreads();
    }
    __syncthreads();   // Plds complete
    // mix + PV phase: wave w = output head g
    #pragma unroll
    for (int mh2 = 0; mh2 < 2; ++mh2) {
      int mof = m0 + mh2 * 32 + lhi * 8;
      bf16x8 vf[6];
      #pragma unroll
      for (int ds = 0; ds < 6; ++ds)
        vf[ds] = *(const bf16x8*)(vtr + (vbase + ds * 16 + l15) * 1024 + mof);
      #pragma unroll
      for (int ns2 = 0; ns2 < 4; ++ns2) {
        float cm8[8];
        #pragma unroll
        for (int j = 0; j < 8; ++j) cm8[j] = cg;
        #pragma unroll
        for (int h = 0; h < 8; ++h) {
          union { u32 ud[4]; bf16x8 bv; } pf;
          pf.bv = *(const bf16x8*)&Plds[((h * 8 + ns2 * 2 + mh2) * 64 + lane) * 8];
          float wgh = wg[h];
          #pragma unroll
          for (int k2 = 0; k2 < 4; ++k2) {
            union { u32 u; float f; } lo, hi;
            lo.u = pf.ud[k2] << 16;
            hi.u = pf.ud[k2] & 0xffff0000u;
            cm8[2 * k2]     += wgh * lo.f;
            cm8[2 * k2 + 1] += wgh * hi.f;
          }
        }
        union { u16 us[8]; bf16x8 bv; } pk2;
        #pragma unroll
        for (int j = 0; j < 8; ++j) {
          sc += cm8[j]; scc += cm8[j] * cm8[j];
          pk2.us[j] = f2bf(cm8[j]);
        }
        #pragma unroll
        for (int ds = 0; ds < 6; ++ds)
          acc[ns2][ds] = mfma16(pk2.bv, vf[ds], acc[ns2][ds]);
      }
    }
    __syncthreads();   // Plds free for next slab
  }

  // BN stat partials: wave g fills cols g and 8+g of this block's row
  #pragma unroll
  for (int off = 32; off > 0; off >>= 1) {
    sc += __shfl_down(sc, off); scc += __shfl_down(scc, off);
  }
  if (lane == 0) { pstat[p * 16 + w] = sc; pstat[p * 16 + 8 + w] = scc; }

  // Coalesced U epilogue: stage each 16n x 768 f32 chunk in Plds (+pad),
  // then write full float4 cachelines.
  float* Uq = (mq == 0) ? U0 : (mq == 1) ? U1 : (mq == 2) ? U2 : U3;
  float* Ust = (float*)Plds;     // 16 x 772 floats = 49408 B <= 64KB
  #pragma unroll 1
  for (int ns2 = 0; ns2 < 4; ++ns2) {
    #pragma unroll
    for (int ds = 0; ds < 6; ++ds)
      #pragma unroll
      for (int r = 0; r < 4; ++r)
        Ust[(lhi * 4 + r) * 772 + w * 96 + ds * 16 + l15] = acc[ns2][ds][r];
    __syncthreads();
    int nbase = ng * 64 + ns2 * 16;
    #pragma unroll
    for (int j = 0; j < 6; ++j) {
      int i4 = t + j * 512;                 // [0, 3072) float4 units
      int row = i4 / 192, c4 = i4 - row * 192;
      float4 v = *(const float4*)&Ust[row * 772 + c4 * 4];
      *(float4*)&Uq[((size_t)(b * 1024 + nbase + row)) * 768 + c4 * 4] = v;
    }
    __syncthreads();
  }
}

// ------------------------------------------------- colsum(V) per (b,h,d), fp32
__global__ __launch_bounds__(384) void k_vcs(const float* __restrict__ vb,
                                             float* __restrict__ vcs)
{
  __shared__ float part[4][96];
  int bh = blockIdx.x, t = threadIdx.x;
  int c = t % 96, g4 = t / 96;
  float a = 0.f;
  const float* vp = vb + (size_t)bh * 98304 + (size_t)g4 * 24576 + c;
  for (int m = 0; m < 256; ++m) a += vp[m * 96];
  part[g4][c] = a;
  __syncthreads();
  if (t < 96) vcs[bh * 96 + t] = part[0][t] + part[1][t] + part[2][t] + part[3][t];
}

// ---------------- BN partial reduce: 256 rows x 16 -> stats[16]
__global__ __launch_bounds__(256) void k_statred(const float* __restrict__ pstat,
                                                 float* __restrict__ stats)
{
  __shared__ float part[16][17];
  int t = threadIdx.x;
  int j = t >> 4, s = t & 15;
  float a = 0.f;
  #pragma unroll
  for (int k2 = 0; k2 < 16; ++k2)
    a += pstat[(size_t)(s + 16 * k2) * 16 + j];
  part[j][s] = a;
  __syncthreads();
  if (t < 16) {
    float v = 0.f;
    #pragma unroll
    for (int s2 = 0; s2 < 16; ++s2) v += part[t][s2];
    stats[t] = v;
  }
}

// ------------- BN affine: ubb = bf16(sg*(U0+U1+U2+U3) + (bnb - sg*mc)*colsum(V))
__global__ __launch_bounds__(256) void k_bnfin(const float* __restrict__ U0,
    const float* __restrict__ U1, const float* __restrict__ U2,
    const float* __restrict__ U3, const float* __restrict__ vcs,
    const float* __restrict__ stats, const float* __restrict__ bng,
    const float* __restrict__ bnb, u16* __restrict__ ubb)
{
  size_t idx = (size_t)blockIdx.x * 256 + threadIdx.x;
  int col = (int)(idx % 768); int i = (int)(idx / 768); int b = i >> 10;
  int g = col / 96, d = col - g * 96;
  const float cnt = 4194304.f;  // B*N*N
  float mc = stats[g] / cnt;
  float var = stats[8 + g] / cnt - mc * mc;
  float sg = bng[g] * rsqrtf(var + EPSV);
  float tg = bnb[g] - sg * mc;
  float u = (U0[idx] + U1[idx]) + (U2[idx] + U3[idx]);
  ubb[idx] = f2bf(sg * u + tg * vcs[(b * 8 + g) * 96 + d]);
}

// -------- bf16 MFMA GEMM: out = A[M,K]@W[N,K]^T + bias (+res)(+gelu)(+LN stats)
template<int GELU_, int RES_, int STATS_, int BF16OUT>
__global__ __launch_bounds__(256) void k_gemm(
    const u16* __restrict__ A, const u16* __restrict__ W,
    const float* __restrict__ bias, const float* __restrict__ res,
    float* __restrict__ out, u16* __restrict__ outb,
    int K, int Nc, float* __restrict__ stats)
{
  __shared__ u16 As[8192], Bs[8192];   // 128 rows x 64 cols, XOR-swizzled
  __shared__ float red[8];
  int t = threadIdx.x, lane = t & 63, wv = t >> 6;
  int l15 = lane & 15, lhi = lane >> 4;
  int i0 = blockIdx.y * 128, j0 = blockIdx.x * 128;
  int wr = wv >> 1, wc = wv & 1;
  f32x4 acc[4][4];
  #pragma unroll
  for (int mi = 0; mi < 4; ++mi)
    #pragma unroll
    for (int ni = 0; ni < 4; ++ni) acc[mi][ni] = (f32x4){0.f, 0.f, 0.f, 0.f};
  int rA = lane >> 3;
  int colel = 8 * ((lane & 7) ^ rA);   // pre-swizzled global source column
  for (int k0 = 0; k0 < K; k0 += 64) {
    if (k0) __syncthreads();
    #pragma unroll
    for (int i = 0; i < 4; ++i) {
      int cA = wv * 4 + i;
      int r = cA * 8 + rA;
      gload16(A + (size_t)(i0 + r) * K + k0 + colel, &As[cA * 512]);
      gload16(W + (size_t)(j0 + r) * K + k0 + colel, &Bs[cA * 512]);
    }
    __syncthreads();
    #pragma unroll
    for (int ks = 0; ks < 2; ++ks) {
      bf16x8 af[4], bf[4];
      #pragma unroll
      for (int mi = 0; mi < 4; ++mi) {
        int r2 = wr * 64 + mi * 16 + l15;
        af[mi] = *(const bf16x8*)&As[r2 * 64 + ((ks * 32 + lhi * 8) ^ (8 * (r2 & 7)))];
      }
      #pragma unroll
      for (int ni = 0; ni < 4; ++ni) {
        int r3 = wc * 64 + ni * 16 + l15;
        bf[ni] = *(const bf16x8*)&Bs[r3 * 64 + ((ks * 32 + lhi * 8) ^ (8 * (r3 & 7)))];
      }
      #pragma unroll
      for (int mi = 0; mi < 4; ++mi)
        #pragma unroll
        for (int ni = 0; ni < 4; ++ni)
          acc[mi][ni] = mfma16(af[mi], bf[ni], acc[mi][ni]);
    }
  }
  float ls = 0.f, lss = 0.f;
  #pragma unroll
  for (int mi = 0; mi < 4; ++mi) {
    #pragma unroll
    for (int ni = 0; ni < 4; ++ni) {
      int col = j0 + wc * 64 + ni * 16 + l15;
      float bv = bias[col];
      #pragma unroll
      for (int r = 0; r < 4; ++r) {
        int row = i0 + wr * 64 + mi * 16 + lhi * 4 + r;
        float val = acc[mi][ni][r] + bv;
        if (RES_) val += res[(size_t)row * Nc + col];
        if (GELU_) val = 0.5f * val * (1.f + erff(val * 0.70710678118654752f));
        if (BF16OUT) outb[(size_t)row * Nc + col] = f2bf(val);
        else out[(size_t)row * Nc + col] = val;
        if (STATS_) { ls += val; lss += val * val; }
      }
    }
  }
  if (STATS_) {
    #pragma unroll
    for (int off = 32; off > 0; off >>= 1) {
      ls += __shfl_down(ls, off); lss += __shfl_down(lss, off);
    }
    if (lane == 0) { red[wv * 2] = ls; red[wv * 2 + 1] = lss; }
    __syncthreads();
    if (t == 0) {
      int b = i0 >> 10;
      atomicAdd(&stats[b * 2],     red[0] + red[2] + red[4] + red[6]);
      atomicAdd(&stats[b * 2 + 1], red[1] + red[3] + red[5] + red[7]);
    }
  }
}

// ------------------------------- joint (N,D) LayerNorm apply (per-b scalars)
template<int BF16OUT>
__global__ __launch_bounds__(256) void k_ln(const float* __restrict__ y,
    const float* __restrict__ stats, const float* __restrict__ g,
    const float* __restrict__ bta, float* __restrict__ outp, u16* __restrict__ outb)
{
  size_t idx = (size_t)blockIdx.x * 256 + threadIdx.x;
  int i = (int)(idx / 768), col = (int)(idx % 768);
  int b = i >> 10, n = i & 1023;
  const float cnt = 786432.f;  // N*D
  float mu = stats[b * 2] / cnt;
  float var = stats[b * 2 + 1] / cnt - mu * mu;
  float r = rsqrtf(var + EPSV);
  size_t gi = (size_t)n * 768 + col;
  float v = (y[idx] - mu) * r * g[gi] + bta[gi];
  outp[idx] = v;
  if (BF16OUT) outb[idx] = f2bf(v);
}

extern "C" void kernel_launch(void* const* d_in, const int* in_sizes, int n_in,
                              void* d_out, int out_size, void* d_ws, size_t ws_size,
                              hipStream_t stream)
{
  const float* x   = (const float*)d_in[0];
  const float* qw  = (const float*)d_in[1];
  const float* kw  = (const float*)d_in[2];
  const float* vw  = (const float*)d_in[3];
  const float* rw  = (const float*)d_in[4];
  const float* bng = (const float*)d_in[6];
  const float* bnb = (const float*)d_in[7];
  const float* pw  = (const float*)d_in[8];
  const float* pb  = (const float*)d_in[9];
  const float* lng = (const float*)d_in[10];
  const float* lnb = (const float*)d_in[11];
  const float* fw1 = (const float*)d_in[12];
  const float* fb1 = (const float*)d_in[13];
  const float* fw2 = (const float*)d_in[14];
  const float* fb2 = (const float*)d_in[15];
  float* out = (float*)d_out;

  float* ws    = (float*)d_ws;
  float* stats = ws;                  // 64 ([0..15] BN, [16..23] LN1, [24..31] LN2)
  float* pstat = ws + 64;             // 4096 (256 blocks x 16)
  float* vcs   = ws + 4160;           // 3072
  float* zp    = ws + 7232;           // 524288 (32 bh x 16 slots x 1024 n)
  float* invZ  = ws + 531520;         // 32768
  float* vb    = ws + 564288;         // 3145728
  float* U0    = ws + 3710016;        // 3145728
  float* U1    = ws + 6855744;        // 3145728
  float* x1    = ws + 10001472;       // 3145728
  u16* u16b = (u16*)(ws + 13147200);
  u16* qhi  = u16b;
  u16* qlo  = u16b + 3145728;
  u16* khi  = u16b + 6291456;
  u16* klo  = u16b + 9437184;
  u16* vtr  = u16b + 12582912;
  u16* ubb  = u16b + 15728640;
  u16* pwb  = u16b + 18874368;
  u16* fw1b = u16b + 19464192;
  u16* fw2b = u16b + 21823488;        // ends 24182784 u16 (~101 MB total)
  float* U2 = vb;                     // vb dead after k_vtr/k_vcs
  float* U3 = x1;                     // x1 written only later by k_ln
  u16* x1b = qhi;                     // attention u16 dead after k_attn2
  u16* hb  = qlo;                     // spans qlo..vtr
  float* y1 = U0;
  float* y2 = vb;

  hipMemsetAsync(stats, 0, 64 * sizeof(float), stream);
  k_f2b<<<1024, 256, 0, stream>>>(pw, pwb, 589824);
  k_f2b<<<2048, 256, 0, stream>>>(fw1, fw1b, 2359296);
  k_f2b<<<2048, 256, 0, stream>>>(fw2, fw2b, 2359296);

  k_conv<<<4096, 256, 0, stream>>>(x, qw, kw, vw, qhi, qlo, khi, klo, vb);
  k_vtr<<<256, 256, 0, stream>>>(vb, vtr);
  k_vcs<<<32, 384, 0, stream>>>(vb, vcs);
  k_zpass<<<512, 512, 0, stream>>>(qhi, qlo, khi, klo, zp);
  k_zmerge<<<128, 256, 0, stream>>>(zp, invZ);
  k_attn2<<<256, 512, 0, stream>>>(qhi, qlo, khi, klo, vtr, invZ, rw,
                                   U0, U1, U2, U3, pstat);
  k_statred<<<1, 256, 0, stream>>>(pstat, stats);
  k_bnfin<<<12288, 256, 0, stream>>>(U0, U1, U2, U3, vcs, stats, bng, bnb, ubb);

  k_gemm<0,1,1,0><<<dim3(6, 32), 256, 0, stream>>>(ubb, pwb, pb, x, y1, nullptr, 768, 768, stats + 16);
  k_ln<1><<<12288, 256, 0, stream>>>(y1, stats + 16, lng, lnb, x1, x1b);
  k_gemm<1,0,0,1><<<dim3(24, 32), 256, 0, stream>>>(x1b, fw1b, fb1, nullptr, nullptr, hb, 768, 3072, nullptr);
  k_gemm<0,1,1,0><<<dim3(6, 32), 256, 0, stream>>>(hb, fw2b, fb2, x1, y2, nullptr, 3072, 768, stats + 24);
  k_ln<0><<<12288, 256, 0, stream>>>(y2, stats + 24, lng, lnb, out, nullptr);
}

// Round 10
// 345.254 us; speedup vs baseline: 1.0834x; 1.0834x over previous
//
#include <hip/hip_runtime.h>
#include <math.h>

// ViT encoder block (DeepViT ReAttention), B=4 N=1024 D=768 H=8 hd=96 Hdim=3072
// R10: fix R9's scratch-demotion bug — the U epilogue's "#pragma unroll 1" over
// ns2 made acc[4][6] runtime-indexed -> whole accumulator demoted to scratch
// (+400MB HBM traffic). Fully unrolled epilogue keeps acc in registers while
// retaining the coalesced full-cacheline U stores.

typedef unsigned short u16;
typedef unsigned int u32;
typedef __bf16 bf16x8 __attribute__((ext_vector_type(8)));
typedef float f32x4 __attribute__((ext_vector_type(4)));

#define EPSV 1e-5f
#define SL2E 0.14724444620253177f   // 96^-0.5 * log2(e), folded into q at conv
#define EXPC -11.541560327111707f   // -8 * log2(e)

__device__ __forceinline__ u16 f2bf(float f) {
  union { float f; u32 u; } v; v.f = f;
  u32 u = v.u + 0x7fffu + ((v.u >> 16) & 1u);
  return (u16)(u >> 16);
}
__device__ __forceinline__ float bf2f(u16 h) {
  union { u32 u; float f; } v; v.u = ((u32)h) << 16; return v.f;
}
__device__ __forceinline__ f32x4 mfma16(bf16x8 a, bf16x8 b, f32x4 c) {
  return __builtin_amdgcn_mfma_f32_16x16x32_bf16(a, b, c, 0, 0, 0);
}
__device__ __forceinline__ void gload16(const void* gp, void* lp) {
  __builtin_amdgcn_global_load_lds(
      (const __attribute__((address_space(1))) u32*)gp,
      (__attribute__((address_space(3))) u32*)lp, 16, 0, 0);
}

// ---- K staging: LINEAR LDS dest (granule G = j*512 + w*64 + lane), source
// address carries the layout permutation (inverse of the frag-native map).
struct KS { int off[3]; int hl[3]; };
__device__ __forceinline__ KS ks_init(int t) {
  KS ks;
  int lane = t & 63;
  int lh = lane >> 4, l15 = lane & 15;
  #pragma unroll
  for (int j = 0; j < 3; ++j) {
    int G = j * 512 + t;                 // granule in [0,1536)
    int hl = (G >= 768) ? 1 : 0;         // 0 = khi half, 1 = klo half
    int C = (G - hl * 768) >> 6;         // uniform per (j,wave)
    int chunk = C / 6, r = C - 6 * chunk;
    int kk = r >> 1, c1 = r & 1;
    int m = chunk * 32 + ((l15 >> 2) << 3) + (c1 << 2) + (l15 & 3);
    ks.off[j] = m * 96 + kk * 32 + lh * 8;
    ks.hl[j] = hl;
  }
  return ks;
}
__device__ __forceinline__ void ks_stage(const u16* __restrict__ khi,
    const u16* __restrict__ klo, size_t rowel, const KS& ks, u16* Kb, int t) {
  int w = t >> 6;
  #pragma unroll
  for (int j = 0; j < 3; ++j) {
    const u16* src = (ks.hl[j] ? klo : khi) + rowel + ks.off[j];
    gload16(src, Kb + (size_t)(j * 512 + w * 64) * 8);
  }
}

__device__ __forceinline__ void qload(const u16* __restrict__ qhi,
    const u16* __restrict__ qlo, size_t qoff, bf16x8* qh, bf16x8* ql) {
  #pragma unroll
  for (int kk = 0; kk < 3; ++kk) {
    qh[kk] = *(const bf16x8*)(qhi + qoff + kk * 32);
    ql[kk] = *(const bf16x8*)(qlo + qoff + kk * 32);
  }
}

// 18-MFMA split-bf16 score pair for one 32m chunk (mh) from staged LDS K.
__device__ __forceinline__ void score18(const u16* Kb, int mh, int lane,
    const bf16x8* qh, const bf16x8* ql, f32x4& C0, f32x4& C1) {
  C0 = (f32x4){0.f, 0.f, 0.f, 0.f};
  C1 = (f32x4){0.f, 0.f, 0.f, 0.f};
  #pragma unroll
  for (int kk = 0; kk < 3; ++kk) {
    const u16* base = Kb + (mh * 6 + kk * 2) * 512 + lane * 8;
    bf16x8 kh0 = *(const bf16x8*)(base);
    bf16x8 kh1 = *(const bf16x8*)(base + 512);
    bf16x8 kl0 = *(const bf16x8*)(base + 6144);
    bf16x8 kl1 = *(const bf16x8*)(base + 6656);
    C0 = mfma16(kh0, qh[kk], C0);
    C0 = mfma16(kl0, qh[kk], C0);
    C0 = mfma16(kh0, ql[kk], C0);
    C1 = mfma16(kh1, qh[kk], C1);
    C1 = mfma16(kl1, qh[kk], C1);
    C1 = mfma16(kh1, ql[kk], C1);
  }
}

// ---------------------------------------------------------------- fp32 -> bf16
__global__ __launch_bounds__(256) void k_f2b(const float* __restrict__ s,
                                             u16* __restrict__ d, int n) {
  int i = blockIdx.x * 256 + threadIdx.x;
  int stride = gridDim.x * 256;
  for (; i < n; i += stride) d[i] = f2bf(s[i]);
}

// ---------------------------------------------------------------- conv 3x3 QKV
__global__ __launch_bounds__(256) void k_conv(const float* __restrict__ x,
    const float* __restrict__ wq, const float* __restrict__ wk, const float* __restrict__ wv,
    u16* __restrict__ qhi, u16* __restrict__ qlo,
    u16* __restrict__ khi, u16* __restrict__ klo,
    float* __restrict__ vb)
{
  __shared__ float patch[768], swq[81], swk[81], swv[81];
  int bid = blockIdx.x;            // b*1024 + n
  int b = bid >> 10, n = bid & 1023;
  int t = threadIdx.x;
  const float* xr = x + (size_t)bid * 768;
  patch[t] = xr[t]; patch[t + 256] = xr[t + 256]; patch[t + 512] = xr[t + 512];
  if (t < 81) { swq[t] = wq[t]; swk[t] = wk[t]; swv[t] = wv[t]; }
  __syncthreads();
  #pragma unroll
  for (int r = 0; r < 3; ++r) {
    int f = t + 256 * r;                       // c*256 + p*16 + q
    int o = f >> 8, rem = f & 255, pp = rem >> 4, qq = rem & 15;
    float aq = 0.f, ak = 0.f, av = 0.f;
    #pragma unroll
    for (int i = 0; i < 3; ++i)
      #pragma unroll
      for (int dp = 0; dp < 3; ++dp) {
        int ip = pp + dp - 1;
        if (ip < 0 || ip > 15) continue;
        #pragma unroll
        for (int dq = 0; dq < 3; ++dq) {
          int iq = qq + dq - 1;
          if (iq < 0 || iq > 15) continue;
          float pv = patch[i * 256 + ip * 16 + iq];
          int wi = ((o * 3 + i) * 3 + dp) * 3 + dq;
          aq += swq[wi] * pv; ak += swk[wi] * pv; av += swv[wi] * pv;
        }
      }
    int h = f / 96, d = f - h * 96;
    size_t oi = ((size_t)(b * 8 + h) * 1024 + n) * 96 + d;
    float aqs = aq * SL2E;           // fold softmax scale + log2e into q
    u16 qh_ = f2bf(aqs); qhi[oi] = qh_; qlo[oi] = f2bf(aqs - bf2f(qh_));
    u16 kh_ = f2bf(ak);  khi[oi] = kh_; klo[oi] = f2bf(ak - bf2f(kh_));
    vb[oi] = av;
  }
}

// ------------------------------- V transpose: [bh][n][d] f32 -> [bh][d][n] bf16
__global__ __launch_bounds__(256) void k_vtr(const float* __restrict__ vb,
                                             u16* __restrict__ vtr)
{
  __shared__ u16 lds[12288];     // [96 d][128 n]
  int bid = blockIdx.x;          // bh*8 + ntile
  int bh = bid >> 3, n0 = (bid & 7) * 128;
  int t = threadIdx.x;
  int n = t >> 1, dh = (t & 1) * 48;
  const float* src = vb + ((size_t)bh * 1024 + n0 + n) * 96 + dh;
  #pragma unroll
  for (int j4 = 0; j4 < 12; ++j4) {
    float4 v = *(const float4*)(src + j4 * 4);
    int d = dh + j4 * 4;
    lds[(d + 0) * 128 + n] = f2bf(v.x);
    lds[(d + 1) * 128 + n] = f2bf(v.y);
    lds[(d + 2) * 128 + n] = f2bf(v.z);
    lds[(d + 3) * 128 + n] = f2bf(v.w);
  }
  __syncthreads();
  #pragma unroll
  for (int j = 0; j < 48; ++j) {
    int flat = t + 256 * j;
    int d = flat >> 7, n2 = flat & 127;
    vtr[((size_t)bh * 96 + d) * 1024 + n0 + n2] = lds[flat];
  }
}

// ---------------- z-pass: zp[bh][slot16][n] = sum_m exp2(C+EXPC) over 64m slabs
__global__ __launch_bounds__(512, 4) void k_zpass(
    const u16* __restrict__ qhi, const u16* __restrict__ qlo,
    const u16* __restrict__ khi, const u16* __restrict__ klo,
    float* __restrict__ zp)
{
  __shared__ u16 Kst[2][12288];
  int p = blockIdx.x;            // 512 blocks
  int s = p >> 3;                // [0,64)
  int c = (p & 7) * 4 + (s >> 4);// [0,32) = (b,mg) combo
  int ng = s & 15;
  int b = c >> 3, mg = c & 7;
  int t = threadIdx.x, lane = t & 63, w = t >> 6;
  int l15 = lane & 15, lhi = lane >> 4;
  int nsub = w >> 1, mh = w & 1;
  int n0 = ng * 64 + nsub * 16;
  int m0base = mg * 128;
  KS ks = ks_init(t);
  bf16x8 qh[3], ql[3], qh2[3], ql2[3];
  size_t bh0 = (size_t)(b * 8) * 1024;
  ks_stage(khi, klo, (bh0 + m0base) * 96, ks, Kst[0], t);
  qload(qhi, qlo, (bh0 + n0 + l15) * 96 + lhi * 8, qh, ql);
  __syncthreads();
  #pragma unroll 1
  for (int h = 0; h < 8; ++h) {
    float z = 0.f;
    #pragma unroll
    for (int mt = 0; mt < 2; ++mt) {
      int u = h * 2 + mt;
      if (u < 15) {   // prefetch next unit into the free buffer
        int un = u + 1, hn = un >> 1, mtn = un & 1;
        size_t bhn = (size_t)(b * 8 + hn) * 1024;
        ks_stage(khi, klo, (bhn + m0base + mtn * 64) * 96, ks, Kst[(u + 1) & 1], t);
        if (mtn == 0)
          qload(qhi, qlo, (bhn + n0 + l15) * 96 + lhi * 8, qh2, ql2);
      }
      f32x4 C0, C1;
      score18(Kst[u & 1], mh, lane, qh, ql, C0, C1);
      #pragma unroll
      for (int r = 0; r < 4; ++r)
        z += exp2f(C0[r] + EXPC) + exp2f(C1[r] + EXPC);
      if (u < 15 && mt == 1) {
        #pragma unroll
        for (int kk = 0; kk < 3; ++kk) { qh[kk] = qh2[kk]; ql[kk] = ql2[kk]; }
      }
      __syncthreads();
    }
    z += __shfl_xor(z, 16);
    z += __shfl_xor(z, 32);
    if (lane < 16)
      zp[((size_t)((b * 8 + h) * 16 + mg * 2 + mh)) * 1024 + n0 + lane] = z;
  }
}

// --------------------------------------- merge 16 z slots -> invZ
__global__ __launch_bounds__(256) void k_zmerge(const float* __restrict__ zp,
                                                float* __restrict__ invZ)
{
  int idx = blockIdx.x * 256 + threadIdx.x;   // < 32768
  int bh = idx >> 10, n = idx & 1023;
  float z = 0.f;
  #pragma unroll
  for (int s = 0; s < 16; ++s) z += zp[((size_t)(bh * 16 + s)) * 1024 + n];
  invZ[idx] = 1.f / z;
}

// ---------------- fused attention: per block (b, 64n, 256m quarter).
__global__ __launch_bounds__(512, 2) void k_attn2(
    const u16* __restrict__ qhi, const u16* __restrict__ qlo,
    const u16* __restrict__ khi, const u16* __restrict__ klo,
    const u16* __restrict__ vtr, const float* __restrict__ invZ,
    const float* __restrict__ rw,
    float* __restrict__ U0, float* __restrict__ U1,
    float* __restrict__ U2, float* __restrict__ U3,
    float* __restrict__ pstat)
{
  __shared__ u16 Kst[2][12288];
  __shared__ u16 Plds[32768];    // [h 8][slot 8][lane 64][8 u16]; reused as U stage
  int p = blockIdx.x;            // 256 blocks
  int s = p >> 3;                // [0,32)
  int c = (p & 7) * 2 + (s >> 4);// [0,16) = (b,mq) combo
  int ng = s & 15;
  int b = c >> 2, mq = c & 3;
  int t = threadIdx.x, lane = t & 63, w = t >> 6;
  int l15 = lane & 15, lhi = lane >> 4;
  int nsub = w >> 1, mh = w & 1;   // head-phase role
  int n0 = ng * 64 + nsub * 16;
  int m0q = mq * 256;
  KS ks = ks_init(t);

  float wg[8]; float wsum = 0.f;
  #pragma unroll
  for (int h = 0; h < 8; ++h) { wg[h] = rw[w * 8 + h]; wsum += wg[h]; }
  float cg = -wsum * (1.f / 1024.f);
  float iz8[8];
  #pragma unroll
  for (int h = 0; h < 8; ++h) iz8[h] = invZ[(b * 8 + h) * 1024 + n0 + l15];
  f32x4 acc[4][6];
  #pragma unroll
  for (int i = 0; i < 4; ++i)
    #pragma unroll
    for (int ds = 0; ds < 6; ++ds) acc[i][ds] = (f32x4){0.f, 0.f, 0.f, 0.f};
  float sc = 0.f, scc = 0.f;
  size_t vbase = (size_t)(b * 8 + w) * 96;

  bf16x8 qh[3], ql[3], qh2[3], ql2[3];
  size_t bh0 = (size_t)(b * 8) * 1024;
  ks_stage(khi, klo, (bh0 + m0q) * 96, ks, Kst[0], t);
  qload(qhi, qlo, (bh0 + n0 + l15) * 96 + lhi * 8, qh, ql);
  __syncthreads();

  #pragma unroll 1
  for (int mt = 0; mt < 4; ++mt) {
    int m0 = m0q + mt * 64;
    #pragma unroll 1
    for (int h = 0; h < 8; ++h) {
      int u = mt * 8 + h;
      if (u < 31) {   // prefetch next unit into the free buffer
        int hn = (h + 1) & 7;
        int mtn = mt + (h == 7 ? 1 : 0);
        size_t bhn = (size_t)(b * 8 + hn) * 1024;
        ks_stage(khi, klo, (bhn + m0q + mtn * 64) * 96, ks, Kst[(u + 1) & 1], t);
        qload(qhi, qlo, (bhn + n0 + l15) * 96 + lhi * 8, qh2, ql2);
      }
      f32x4 C0, C1;
      score18(Kst[u & 1], mh, lane, qh, ql, C0, C1);
      float iz = iz8[h];
      union { u16 us[8]; bf16x8 bv; } pk;
      #pragma unroll
      for (int r = 0; r < 4; ++r) {
        pk.us[r]     = f2bf(exp2f(C0[r] + EXPC) * iz);
        pk.us[4 + r] = f2bf(exp2f(C1[r] + EXPC) * iz);
      }
      *(bf16x8*)&Plds[((h * 8 + w) * 64 + lane) * 8] = pk.bv;
      if (u < 31) {
        #pragma unroll
        for (int kk = 0; kk < 3; ++kk) { qh[kk] = qh2[kk]; ql[kk] = ql2[kk]; }
      }
      if (h < 7) __syncthreads();
    }
    __syncthreads();   // Plds complete
    // mix + PV phase: wave w = output head g
    #pragma unroll
    for (int mh2 = 0; mh2 < 2; ++mh2) {
      int mof = m0 + mh2 * 32 + lhi * 8;
      bf16x8 vf[6];
      #pragma unroll
      for (int ds = 0; ds < 6; ++ds)
        vf[ds] = *(const bf16x8*)(vtr + (vbase + ds * 16 + l15) * 1024 + mof);
      #pragma unroll
      for (int ns2 = 0; ns2 < 4; ++ns2) {
        float cm8[8];
        #pragma unroll
        for (int j = 0; j < 8; ++j) cm8[j] = cg;
        #pragma unroll
        for (int h = 0; h < 8; ++h) {
          union { u32 ud[4]; bf16x8 bv; } pf;
          pf.bv = *(const bf16x8*)&Plds[((h * 8 + ns2 * 2 + mh2) * 64 + lane) * 8];
          float wgh = wg[h];
          #pragma unroll
          for (int k2 = 0; k2 < 4; ++k2) {
            union { u32 u; float f; } lo, hi;
            lo.u = pf.ud[k2] << 16;
            hi.u = pf.ud[k2] & 0xffff0000u;
            cm8[2 * k2]     += wgh * lo.f;
            cm8[2 * k2 + 1] += wgh * hi.f;
          }
        }
        union { u16 us[8]; bf16x8 bv; } pk2;
        #pragma unroll
        for (int j = 0; j < 8; ++j) {
          sc += cm8[j]; scc += cm8[j] * cm8[j];
          pk2.us[j] = f2bf(cm8[j]);
        }
        #pragma unroll
        for (int ds = 0; ds < 6; ++ds)
          acc[ns2][ds] = mfma16(pk2.bv, vf[ds], acc[ns2][ds]);
      }
    }
    __syncthreads();   // Plds free for next slab
  }

  // BN stat partials: wave g fills cols g and 8+g of this block's row
  #pragma unroll
  for (int off = 32; off > 0; off >>= 1) {
    sc += __shfl_down(sc, off); scc += __shfl_down(scc, off);
  }
  if (lane == 0) { pstat[p * 16 + w] = sc; pstat[p * 16 + 8 + w] = scc; }

  // Coalesced U epilogue: stage each 16n x 768 f32 chunk in Plds (+pad),
  // then write full float4 cachelines. FULLY UNROLLED (compile-time acc idx —
  // "#pragma unroll 1" here demoted acc to scratch in R9, +400MB traffic).
  float* Uq = (mq == 0) ? U0 : (mq == 1) ? U1 : (mq == 2) ? U2 : U3;
  float* Ust = (float*)Plds;     // 16 x 772 floats = 49408 B <= 64KB
  #pragma unroll
  for (int ns2 = 0; ns2 < 4; ++ns2) {
    #pragma unroll
    for (int ds = 0; ds < 6; ++ds)
      #pragma unroll
      for (int r = 0; r < 4; ++r)
        Ust[(lhi * 4 + r) * 772 + w * 96 + ds * 16 + l15] = acc[ns2][ds][r];
    __syncthreads();
    int nbase = ng * 64 + ns2 * 16;
    #pragma unroll
    for (int j = 0; j < 6; ++j) {
      int i4 = t + j * 512;                 // [0, 3072) float4 units
      int row = i4 / 192, c4 = i4 - row * 192;
      float4 v = *(const float4*)&Ust[row * 772 + c4 * 4];
      *(float4*)&Uq[((size_t)(b * 1024 + nbase + row)) * 768 + c4 * 4] = v;
    }
    __syncthreads();
  }
}

// ------------------------------------------------- colsum(V) per (b,h,d), fp32
__global__ __launch_bounds__(384) void k_vcs(const float* __restrict__ vb,
                                             float* __restrict__ vcs)
{
  __shared__ float part[4][96];
  int bh = blockIdx.x, t = threadIdx.x;
  int c = t % 96, g4 = t / 96;
  float a = 0.f;
  const float* vp = vb + (size_t)bh * 98304 + (size_t)g4 * 24576 + c;
  for (int m = 0; m < 256; ++m) a += vp[m * 96];
  part[g4][c] = a;
  __syncthreads();
  if (t < 96) vcs[bh * 96 + t] = part[0][t] + part[1][t] + part[2][t] + part[3][t];
}

// ---------------- BN partial reduce: 256 rows x 16 -> stats[16]
__global__ __launch_bounds__(256) void k_statred(const float* __restrict__ pstat,
                                                 float* __restrict__ stats)
{
  __shared__ float part[16][17];
  int t = threadIdx.x;
  int j = t >> 4, s = t & 15;
  float a = 0.f;
  #pragma unroll
  for (int k2 = 0; k2 < 16; ++k2)
    a += pstat[(size_t)(s + 16 * k2) * 16 + j];
  part[j][s] = a;
  __syncthreads();
  if (t < 16) {
    float v = 0.f;
    #pragma unroll
    for (int s2 = 0; s2 < 16; ++s2) v += part[t][s2];
    stats[t] = v;
  }
}

// ------------- BN affine: ubb = bf16(sg*(U0+U1+U2+U3) + (bnb - sg*mc)*colsum(V))
__global__ __launch_bounds__(256) void k_bnfin(const float* __restrict__ U0,
    const float* __restrict__ U1, const float* __restrict__ U2,
    const float* __restrict__ U3, const float* __restrict__ vcs,
    const float* __restrict__ stats, const float* __restrict__ bng,
    const float* __restrict__ bnb, u16* __restrict__ ubb)
{
  size_t idx = (size_t)blockIdx.x * 256 + threadIdx.x;
  int col = (int)(idx % 768); int i = (int)(idx / 768); int b = i >> 10;
  int g = col / 96, d = col - g * 96;
  const float cnt = 4194304.f;  // B*N*N
  float mc = stats[g] / cnt;
  float var = stats[8 + g] / cnt - mc * mc;
  float sg = bng[g] * rsqrtf(var + EPSV);
  float tg = bnb[g] - sg * mc;
  float u = (U0[idx] + U1[idx]) + (U2[idx] + U3[idx]);
  ubb[idx] = f2bf(sg * u + tg * vcs[(b * 8 + g) * 96 + d]);
}

// -------- bf16 MFMA GEMM: out = A[M,K]@W[N,K]^T + bias (+res)(+gelu)(+LN stats)
template<int GELU_, int RES_, int STATS_, int BF16OUT>
__global__ __launch_bounds__(256) void k_gemm(
    const u16* __restrict__ A, const u16* __restrict__ W,
    const float* __restrict__ bias, const float* __restrict__ res,
    float* __restrict__ out, u16* __restrict__ outb,
    int K, int Nc, float* __restrict__ stats)
{
  __shared__ u16 As[8192], Bs[8192];   // 128 rows x 64 cols, XOR-swizzled
  __shared__ float red[8];
  int t = threadIdx.x, lane = t & 63, wv = t >> 6;
  int l15 = lane & 15, lhi = lane >> 4;
  int i0 = blockIdx.y * 128, j0 = blockIdx.x * 128;
  int wr = wv >> 1, wc = wv & 1;
  f32x4 acc[4][4];
  #pragma unroll
  for (int mi = 0; mi < 4; ++mi)
    #pragma unroll
    for (int ni = 0; ni < 4; ++ni) acc[mi][ni] = (f32x4){0.f, 0.f, 0.f, 0.f};
  int rA = lane >> 3;
  int colel = 8 * ((lane & 7) ^ rA);   // pre-swizzled global source column
  for (int k0 = 0; k0 < K; k0 += 64) {
    if (k0) __syncthreads();
    #pragma unroll
    for (int i = 0; i < 4; ++i) {
      int cA = wv * 4 + i;
      int r = cA * 8 + rA;
      gload16(A + (size_t)(i0 + r) * K + k0 + colel, &As[cA * 512]);
      gload16(W + (size_t)(j0 + r) * K + k0 + colel, &Bs[cA * 512]);
    }
    __syncthreads();
    #pragma unroll
    for (int ks = 0; ks < 2; ++ks) {
      bf16x8 af[4], bf[4];
      #pragma unroll
      for (int mi = 0; mi < 4; ++mi) {
        int r2 = wr * 64 + mi * 16 + l15;
        af[mi] = *(const bf16x8*)&As[r2 * 64 + ((ks * 32 + lhi * 8) ^ (8 * (r2 & 7)))];
      }
      #pragma unroll
      for (int ni = 0; ni < 4; ++ni) {
        int r3 = wc * 64 + ni * 16 + l15;
        bf[ni] = *(const bf16x8*)&Bs[r3 * 64 + ((ks * 32 + lhi * 8) ^ (8 * (r3 & 7)))];
      }
      #pragma unroll
      for (int mi = 0; mi < 4; ++mi)
        #pragma unroll
        for (int ni = 0; ni < 4; ++ni)
          acc[mi][ni] = mfma16(af[mi], bf[ni], acc[mi][ni]);
    }
  }
  float ls = 0.f, lss = 0.f;
  #pragma unroll
  for (int mi = 0; mi < 4; ++mi) {
    #pragma unroll
    for (int ni = 0; ni < 4; ++ni) {
      int col = j0 + wc * 64 + ni * 16 + l15;
      float bv = bias[col];
      #pragma unroll
      for (int r = 0; r < 4; ++r) {
        int row = i0 + wr * 64 + mi * 16 + lhi * 4 + r;
        float val = acc[mi][ni][r] + bv;
        if (RES_) val += res[(size_t)row * Nc + col];
        if (GELU_) val = 0.5f * val * (1.f + erff(val * 0.70710678118654752f));
        if (BF16OUT) outb[(size_t)row * Nc + col] = f2bf(val);
        else out[(size_t)row * Nc + col] = val;
        if (STATS_) { ls += val; lss += val * val; }
      }
    }
  }
  if (STATS_) {
    #pragma unroll
    for (int off = 32; off > 0; off >>= 1) {
      ls += __shfl_down(ls, off); lss += __shfl_down(lss, off);
    }
    if (lane == 0) { red[wv * 2] = ls; red[wv * 2 + 1] = lss; }
    __syncthreads();
    if (t == 0) {
      int b = i0 >> 10;
      atomicAdd(&stats[b * 2],     red[0] + red[2] + red[4] + red[6]);
      atomicAdd(&stats[b * 2 + 1], red[1] + red[3] + red[5] + red[7]);
    }
  }
}

// ------------------------------- joint (N,D) LayerNorm apply (per-b scalars)
template<int BF16OUT>
__global__ __launch_bounds__(256) void k_ln(const float* __restrict__ y,
    const float* __restrict__ stats, const float* __restrict__ g,
    const float* __restrict__ bta, float* __restrict__ outp, u16* __restrict__ outb)
{
  size_t idx = (size_t)blockIdx.x * 256 + threadIdx.x;
  int i = (int)(idx / 768), col = (int)(idx % 768);
  int b = i >> 10, n = i & 1023;
  const float cnt = 786432.f;  // N*D
  float mu = stats[b * 2] / cnt;
  float var = stats[b * 2 + 1] / cnt - mu * mu;
  float r = rsqrtf(var + EPSV);
  size_t gi = (size_t)n * 768 + col;
  float v = (y[idx] - mu) * r * g[gi] + bta[gi];
  outp[idx] = v;
  if (BF16OUT) outb[idx] = f2bf(v);
}

extern "C" void kernel_launch(void* const* d_in, const int* in_sizes, int n_in,
                              void* d_out, int out_size, void* d_ws, size_t ws_size,
                              hipStream_t stream)
{
  const float* x   = (const float*)d_in[0];
  const float* qw  = (const float*)d_in[1];
  const float* kw  = (const float*)d_in[2];
  const float* vw  = (const float*)d_in[3];
  const float* rw  = (const float*)d_in[4];
  const float* bng = (const float*)d_in[6];
  const float* bnb = (const float*)d_in[7];
  const float* pw  = (const float*)d_in[8];
  const float* pb  = (const float*)d_in[9];
  const float* lng = (const float*)d_in[10];
  const float* lnb = (const float*)d_in[11];
  const float* fw1 = (const float*)d_in[12];
  const float* fb1 = (const float*)d_in[13];
  const float* fw2 = (const float*)d_in[14];
  const float* fb2 = (const float*)d_in[15];
  float* out = (float*)d_out;

  float* ws    = (float*)d_ws;
  float* stats = ws;                  // 64 ([0..15] BN, [16..23] LN1, [24..31] LN2)
  float* pstat = ws + 64;             // 4096 (256 blocks x 16)
  float* vcs   = ws + 4160;           // 3072
  float* zp    = ws + 7232;           // 524288 (32 bh x 16 slots x 1024 n)
  float* invZ  = ws + 531520;         // 32768
  float* vb    = ws + 564288;         // 3145728
  float* U0    = ws + 3710016;        // 3145728
  float* U1    = ws + 6855744;        // 3145728
  float* x1    = ws + 10001472;       // 3145728
  u16* u16b = (u16*)(ws + 13147200);
  u16* qhi  = u16b;
  u16* qlo  = u16b + 3145728;
  u16* khi  = u16b + 6291456;
  u16* klo  = u16b + 9437184;
  u16* vtr  = u16b + 12582912;
  u16* ubb  = u16b + 15728640;
  u16* pwb  = u16b + 18874368;
  u16* fw1b = u16b + 19464192;
  u16* fw2b = u16b + 21823488;        // ends 24182784 u16 (~101 MB total)
  float* U2 = vb;                     // vb dead after k_vtr/k_vcs
  float* U3 = x1;                     // x1 written only later by k_ln
  u16* x1b = qhi;                     // attention u16 dead after k_attn2
  u16* hb  = qlo;                     // spans qlo..vtr
  float* y1 = U0;
  float* y2 = vb;

  hipMemsetAsync(stats, 0, 64 * sizeof(float), stream);
  k_f2b<<<1024, 256, 0, stream>>>(pw, pwb, 589824);
  k_f2b<<<2048, 256, 0, stream>>>(fw1, fw1b, 2359296);
  k_f2b<<<2048, 256, 0, stream>>>(fw2, fw2b, 2359296);

  k_conv<<<4096, 256, 0, stream>>>(x, qw, kw, vw, qhi, qlo, khi, klo, vb);
  k_vtr<<<256, 256, 0, stream>>>(vb, vtr);
  k_vcs<<<32, 384, 0, stream>>>(vb, vcs);
  k_zpass<<<512, 512, 0, stream>>>(qhi, qlo, khi, klo, zp);
  k_zmerge<<<128, 256, 0, stream>>>(zp, invZ);
  k_attn2<<<256, 512, 0, stream>>>(qhi, qlo, khi, klo, vtr, invZ, rw,
                                   U0, U1, U2, U3, pstat);
  k_statred<<<1, 256, 0, stream>>>(pstat, stats);
  k_bnfin<<<12288, 256, 0, stream>>>(U0, U1, U2, U3, vcs, stats, bng, bnb, ubb);

  k_gemm<0,1,1,0><<<dim3(6, 32), 256, 0, stream>>>(ubb, pwb, pb, x, y1, nullptr, 768, 768, stats + 16);
  k_ln<1><<<12288, 256, 0, stream>>>(y1, stats + 16, lng, lnb, x1, x1b);
  k_gemm<1,0,0,1><<<dim3(24, 32), 256, 0, stream>>>(x1b, fw1b, fb1, nullptr, nullptr, hb, 768, 3072, nullptr);
  k_gemm<0,1,1,0><<<dim3(6, 32), 256, 0, stream>>>(hb, fw2b, fb2, x1, y2, nullptr, 3072, 768, stats + 24);
  k_ln<0><<<12288, 256, 0, stream>>>(y2, stats + 24, lng, lnb, out, nullptr);
}

// Round 11
// 344.728 us; speedup vs baseline: 1.0850x; 1.0015x over previous
//
#include <hip/hip_runtime.h>
#include <math.h>

// ViT encoder block (DeepViT ReAttention), B=4 N=1024 D=768 H=8 hd=96 Hdim=3072
// R11: remove the VGPR cap that forced acc[4][6] into scratch since R7.
// hipcc treats __launch_bounds__ arg2 as min-blocks/CU: (512,2) => 128-VGPR cap,
// but k_attn2's live set is ~200 regs -> PV accumulator spilled, +100MB phantom
// HBM writes. LDS (112KB) already limits to 1 block/CU, so drop the bound and
// let the allocator use 256 VGPRs. zpass relaxed (512,4)->(512,2) similarly.

typedef unsigned short u16;
typedef unsigned int u32;
typedef __bf16 bf16x8 __attribute__((ext_vector_type(8)));
typedef float f32x4 __attribute__((ext_vector_type(4)));

#define EPSV 1e-5f
#define SL2E 0.14724444620253177f   // 96^-0.5 * log2(e), folded into q at conv
#define EXPC -11.541560327111707f   // -8 * log2(e)

__device__ __forceinline__ u16 f2bf(float f) {
  union { float f; u32 u; } v; v.f = f;
  u32 u = v.u + 0x7fffu + ((v.u >> 16) & 1u);
  return (u16)(u >> 16);
}
__device__ __forceinline__ float bf2f(u16 h) {
  union { u32 u; float f; } v; v.u = ((u32)h) << 16; return v.f;
}
__device__ __forceinline__ f32x4 mfma16(bf16x8 a, bf16x8 b, f32x4 c) {
  return __builtin_amdgcn_mfma_f32_16x16x32_bf16(a, b, c, 0, 0, 0);
}
__device__ __forceinline__ void gload16(const void* gp, void* lp) {
  __builtin_amdgcn_global_load_lds(
      (const __attribute__((address_space(1))) u32*)gp,
      (__attribute__((address_space(3))) u32*)lp, 16, 0, 0);
}

// ---- K staging: LINEAR LDS dest (granule G = j*512 + w*64 + lane), source
// address carries the layout permutation (inverse of the frag-native map).
struct KS { int off[3]; int hl[3]; };
__device__ __forceinline__ KS ks_init(int t) {
  KS ks;
  int lane = t & 63;
  int lh = lane >> 4, l15 = lane & 15;
  #pragma unroll
  for (int j = 0; j < 3; ++j) {
    int G = j * 512 + t;                 // granule in [0,1536)
    int hl = (G >= 768) ? 1 : 0;         // 0 = khi half, 1 = klo half
    int C = (G - hl * 768) >> 6;         // uniform per (j,wave)
    int chunk = C / 6, r = C - 6 * chunk;
    int kk = r >> 1, c1 = r & 1;
    int m = chunk * 32 + ((l15 >> 2) << 3) + (c1 << 2) + (l15 & 3);
    ks.off[j] = m * 96 + kk * 32 + lh * 8;
    ks.hl[j] = hl;
  }
  return ks;
}
__device__ __forceinline__ void ks_stage(const u16* __restrict__ khi,
    const u16* __restrict__ klo, size_t rowel, const KS& ks, u16* Kb, int t) {
  int w = t >> 6;
  #pragma unroll
  for (int j = 0; j < 3; ++j) {
    const u16* src = (ks.hl[j] ? klo : khi) + rowel + ks.off[j];
    gload16(src, Kb + (size_t)(j * 512 + w * 64) * 8);
  }
}

__device__ __forceinline__ void qload(const u16* __restrict__ qhi,
    const u16* __restrict__ qlo, size_t qoff, bf16x8* qh, bf16x8* ql) {
  #pragma unroll
  for (int kk = 0; kk < 3; ++kk) {
    qh[kk] = *(const bf16x8*)(qhi + qoff + kk * 32);
    ql[kk] = *(const bf16x8*)(qlo + qoff + kk * 32);
  }
}

// 18-MFMA split-bf16 score pair for one 32m chunk (mh) from staged LDS K.
__device__ __forceinline__ void score18(const u16* Kb, int mh, int lane,
    const bf16x8* qh, const bf16x8* ql, f32x4& C0, f32x4& C1) {
  C0 = (f32x4){0.f, 0.f, 0.f, 0.f};
  C1 = (f32x4){0.f, 0.f, 0.f, 0.f};
  #pragma unroll
  for (int kk = 0; kk < 3; ++kk) {
    const u16* base = Kb + (mh * 6 + kk * 2) * 512 + lane * 8;
    bf16x8 kh0 = *(const bf16x8*)(base);
    bf16x8 kh1 = *(const bf16x8*)(base + 512);
    bf16x8 kl0 = *(const bf16x8*)(base + 6144);
    bf16x8 kl1 = *(const bf16x8*)(base + 6656);
    C0 = mfma16(kh0, qh[kk], C0);
    C0 = mfma16(kl0, qh[kk], C0);
    C0 = mfma16(kh0, ql[kk], C0);
    C1 = mfma16(kh1, qh[kk], C1);
    C1 = mfma16(kl1, qh[kk], C1);
    C1 = mfma16(kh1, ql[kk], C1);
  }
}

// ---------------------------------------------------------------- fp32 -> bf16
__global__ __launch_bounds__(256) void k_f2b(const float* __restrict__ s,
                                             u16* __restrict__ d, int n) {
  int i = blockIdx.x * 256 + threadIdx.x;
  int stride = gridDim.x * 256;
  for (; i < n; i += stride) d[i] = f2bf(s[i]);
}

// ---------------------------------------------------------------- conv 3x3 QKV
__global__ __launch_bounds__(256) void k_conv(const float* __restrict__ x,
    const float* __restrict__ wq, const float* __restrict__ wk, const float* __restrict__ wv,
    u16* __restrict__ qhi, u16* __restrict__ qlo,
    u16* __restrict__ khi, u16* __restrict__ klo,
    float* __restrict__ vb)
{
  __shared__ float patch[768], swq[81], swk[81], swv[81];
  int bid = blockIdx.x;            // b*1024 + n
  int b = bid >> 10, n = bid & 1023;
  int t = threadIdx.x;
  const float* xr = x + (size_t)bid * 768;
  patch[t] = xr[t]; patch[t + 256] = xr[t + 256]; patch[t + 512] = xr[t + 512];
  if (t < 81) { swq[t] = wq[t]; swk[t] = wk[t]; swv[t] = wv[t]; }
  __syncthreads();
  #pragma unroll
  for (int r = 0; r < 3; ++r) {
    int f = t + 256 * r;                       // c*256 + p*16 + q
    int o = f >> 8, rem = f & 255, pp = rem >> 4, qq = rem & 15;
    float aq = 0.f, ak = 0.f, av = 0.f;
    #pragma unroll
    for (int i = 0; i < 3; ++i)
      #pragma unroll
      for (int dp = 0; dp < 3; ++dp) {
        int ip = pp + dp - 1;
        if (ip < 0 || ip > 15) continue;
        #pragma unroll
        for (int dq = 0; dq < 3; ++dq) {
          int iq = qq + dq - 1;
          if (iq < 0 || iq > 15) continue;
          float pv = patch[i * 256 + ip * 16 + iq];
          int wi = ((o * 3 + i) * 3 + dp) * 3 + dq;
          aq += swq[wi] * pv; ak += swk[wi] * pv; av += swv[wi] * pv;
        }
      }
    int h = f / 96, d = f - h * 96;
    size_t oi = ((size_t)(b * 8 + h) * 1024 + n) * 96 + d;
    float aqs = aq * SL2E;           // fold softmax scale + log2e into q
    u16 qh_ = f2bf(aqs); qhi[oi] = qh_; qlo[oi] = f2bf(aqs - bf2f(qh_));
    u16 kh_ = f2bf(ak);  khi[oi] = kh_; klo[oi] = f2bf(ak - bf2f(kh_));
    vb[oi] = av;
  }
}

// ------------------------------- V transpose: [bh][n][d] f32 -> [bh][d][n] bf16
__global__ __launch_bounds__(256) void k_vtr(const float* __restrict__ vb,
                                             u16* __restrict__ vtr)
{
  __shared__ u16 lds[12288];     // [96 d][128 n]
  int bid = blockIdx.x;          // bh*8 + ntile
  int bh = bid >> 3, n0 = (bid & 7) * 128;
  int t = threadIdx.x;
  int n = t >> 1, dh = (t & 1) * 48;
  const float* src = vb + ((size_t)bh * 1024 + n0 + n) * 96 + dh;
  #pragma unroll
  for (int j4 = 0; j4 < 12; ++j4) {
    float4 v = *(const float4*)(src + j4 * 4);
    int d = dh + j4 * 4;
    lds[(d + 0) * 128 + n] = f2bf(v.x);
    lds[(d + 1) * 128 + n] = f2bf(v.y);
    lds[(d + 2) * 128 + n] = f2bf(v.z);
    lds[(d + 3) * 128 + n] = f2bf(v.w);
  }
  __syncthreads();
  #pragma unroll
  for (int j = 0; j < 48; ++j) {
    int flat = t + 256 * j;
    int d = flat >> 7, n2 = flat & 127;
    vtr[((size_t)bh * 96 + d) * 1024 + n0 + n2] = lds[flat];
  }
}

// ---------------- z-pass: zp[bh][slot16][n] = sum_m exp2(C+EXPC) over 64m slabs
__global__ __launch_bounds__(512, 2) void k_zpass(
    const u16* __restrict__ qhi, const u16* __restrict__ qlo,
    const u16* __restrict__ khi, const u16* __restrict__ klo,
    float* __restrict__ zp)
{
  __shared__ u16 Kst[2][12288];
  int p = blockIdx.x;            // 512 blocks
  int s = p >> 3;                // [0,64)
  int c = (p & 7) * 4 + (s >> 4);// [0,32) = (b,mg) combo
  int ng = s & 15;
  int b = c >> 3, mg = c & 7;
  int t = threadIdx.x, lane = t & 63, w = t >> 6;
  int l15 = lane & 15, lhi = lane >> 4;
  int nsub = w >> 1, mh = w & 1;
  int n0 = ng * 64 + nsub * 16;
  int m0base = mg * 128;
  KS ks = ks_init(t);
  bf16x8 qh[3], ql[3], qh2[3], ql2[3];
  size_t bh0 = (size_t)(b * 8) * 1024;
  ks_stage(khi, klo, (bh0 + m0base) * 96, ks, Kst[0], t);
  qload(qhi, qlo, (bh0 + n0 + l15) * 96 + lhi * 8, qh, ql);
  __syncthreads();
  #pragma unroll 1
  for (int h = 0; h < 8; ++h) {
    float z = 0.f;
    #pragma unroll
    for (int mt = 0; mt < 2; ++mt) {
      int u = h * 2 + mt;
      if (u < 15) {   // prefetch next unit into the free buffer
        int un = u + 1, hn = un >> 1, mtn = un & 1;
        size_t bhn = (size_t)(b * 8 + hn) * 1024;
        ks_stage(khi, klo, (bhn + m0base + mtn * 64) * 96, ks, Kst[(u + 1) & 1], t);
        if (mtn == 0)
          qload(qhi, qlo, (bhn + n0 + l15) * 96 + lhi * 8, qh2, ql2);
      }
      f32x4 C0, C1;
      score18(Kst[u & 1], mh, lane, qh, ql, C0, C1);
      #pragma unroll
      for (int r = 0; r < 4; ++r)
        z += exp2f(C0[r] + EXPC) + exp2f(C1[r] + EXPC);
      if (u < 15 && mt == 1) {
        #pragma unroll
        for (int kk = 0; kk < 3; ++kk) { qh[kk] = qh2[kk]; ql[kk] = ql2[kk]; }
      }
      __syncthreads();
    }
    z += __shfl_xor(z, 16);
    z += __shfl_xor(z, 32);
    if (lane < 16)
      zp[((size_t)((b * 8 + h) * 16 + mg * 2 + mh)) * 1024 + n0 + lane] = z;
  }
}

// --------------------------------------- merge 16 z slots -> invZ
__global__ __launch_bounds__(256) void k_zmerge(const float* __restrict__ zp,
                                                float* __restrict__ invZ)
{
  int idx = blockIdx.x * 256 + threadIdx.x;   // < 32768
  int bh = idx >> 10, n = idx & 1023;
  float z = 0.f;
  #pragma unroll
  for (int s = 0; s < 16; ++s) z += zp[((size_t)(bh * 16 + s)) * 1024 + n];
  invZ[idx] = 1.f / z;
}

// ---------------- fused attention: per block (b, 64n, 256m quarter).
// No launch-bounds min-block cap: LDS (112KB) limits to 1 block/CU anyway,
// so the allocator may use up to 256 VGPRs (acc stays in registers).
__global__ __launch_bounds__(512) void k_attn2(
    const u16* __restrict__ qhi, const u16* __restrict__ qlo,
    const u16* __restrict__ khi, const u16* __restrict__ klo,
    const u16* __restrict__ vtr, const float* __restrict__ invZ,
    const float* __restrict__ rw,
    float* __restrict__ U0, float* __restrict__ U1,
    float* __restrict__ U2, float* __restrict__ U3,
    float* __restrict__ pstat)
{
  __shared__ u16 Kst[2][12288];
  __shared__ u16 Plds[32768];    // [h 8][slot 8][lane 64][8 u16]; reused as U stage
  int p = blockIdx.x;            // 256 blocks
  int s = p >> 3;                // [0,32)
  int c = (p & 7) * 2 + (s >> 4);// [0,16) = (b,mq) combo
  int ng = s & 15;
  int b = c >> 2, mq = c & 3;
  int t = threadIdx.x, lane = t & 63, w = t >> 6;
  int l15 = lane & 15, lhi = lane >> 4;
  int nsub = w >> 1, mh = w & 1;   // head-phase role
  int n0 = ng * 64 + nsub * 16;
  int m0q = mq * 256;
  KS ks = ks_init(t);

  float wg[8]; float wsum = 0.f;
  #pragma unroll
  for (int h = 0; h < 8; ++h) { wg[h] = rw[w * 8 + h]; wsum += wg[h]; }
  float cg = -wsum * (1.f / 1024.f);
  float iz8[8];
  #pragma unroll
  for (int h = 0; h < 8; ++h) iz8[h] = invZ[(b * 8 + h) * 1024 + n0 + l15];
  f32x4 acc[4][6];
  #pragma unroll
  for (int i = 0; i < 4; ++i)
    #pragma unroll
    for (int ds = 0; ds < 6; ++ds) acc[i][ds] = (f32x4){0.f, 0.f, 0.f, 0.f};
  float sc = 0.f, scc = 0.f;
  size_t vbase = (size_t)(b * 8 + w) * 96;

  bf16x8 qh[3], ql[3], qh2[3], ql2[3];
  size_t bh0 = (size_t)(b * 8) * 1024;
  ks_stage(khi, klo, (bh0 + m0q) * 96, ks, Kst[0], t);
  qload(qhi, qlo, (bh0 + n0 + l15) * 96 + lhi * 8, qh, ql);
  __syncthreads();

  #pragma unroll 1
  for (int mt = 0; mt < 4; ++mt) {
    int m0 = m0q + mt * 64;
    #pragma unroll 1
    for (int h = 0; h < 8; ++h) {
      int u = mt * 8 + h;
      if (u < 31) {   // prefetch next unit into the free buffer
        int hn = (h + 1) & 7;
        int mtn = mt + (h == 7 ? 1 : 0);
        size_t bhn = (size_t)(b * 8 + hn) * 1024;
        ks_stage(khi, klo, (bhn + m0q + mtn * 64) * 96, ks, Kst[(u + 1) & 1], t);
        qload(qhi, qlo, (bhn + n0 + l15) * 96 + lhi * 8, qh2, ql2);
      }
      f32x4 C0, C1;
      score18(Kst[u & 1], mh, lane, qh, ql, C0, C1);
      float iz = iz8[h];
      union { u16 us[8]; bf16x8 bv; } pk;
      #pragma unroll
      for (int r = 0; r < 4; ++r) {
        pk.us[r]     = f2bf(exp2f(C0[r] + EXPC) * iz);
        pk.us[4 + r] = f2bf(exp2f(C1[r] + EXPC) * iz);
      }
      *(bf16x8*)&Plds[((h * 8 + w) * 64 + lane) * 8] = pk.bv;
      if (u < 31) {
        #pragma unroll
        for (int kk = 0; kk < 3; ++kk) { qh[kk] = qh2[kk]; ql[kk] = ql2[kk]; }
      }
      if (h < 7) __syncthreads();
    }
    __syncthreads();   // Plds complete
    // mix + PV phase: wave w = output head g
    #pragma unroll
    for (int mh2 = 0; mh2 < 2; ++mh2) {
      int mof = m0 + mh2 * 32 + lhi * 8;
      bf16x8 vf[6];
      #pragma unroll
      for (int ds = 0; ds < 6; ++ds)
        vf[ds] = *(const bf16x8*)(vtr + (vbase + ds * 16 + l15) * 1024 + mof);
      #pragma unroll
      for (int ns2 = 0; ns2 < 4; ++ns2) {
        float cm8[8];
        #pragma unroll
        for (int j = 0; j < 8; ++j) cm8[j] = cg;
        #pragma unroll
        for (int h = 0; h < 8; ++h) {
          union { u32 ud[4]; bf16x8 bv; } pf;
          pf.bv = *(const bf16x8*)&Plds[((h * 8 + ns2 * 2 + mh2) * 64 + lane) * 8];
          float wgh = wg[h];
          #pragma unroll
          for (int k2 = 0; k2 < 4; ++k2) {
            union { u32 u; float f; } lo, hi;
            lo.u = pf.ud[k2] << 16;
            hi.u = pf.ud[k2] & 0xffff0000u;
            cm8[2 * k2]     += wgh * lo.f;
            cm8[2 * k2 + 1] += wgh * hi.f;
          }
        }
        union { u16 us[8]; bf16x8 bv; } pk2;
        #pragma unroll
        for (int j = 0; j < 8; ++j) {
          sc += cm8[j]; scc += cm8[j] * cm8[j];
          pk2.us[j] = f2bf(cm8[j]);
        }
        #pragma unroll
        for (int ds = 0; ds < 6; ++ds)
          acc[ns2][ds] = mfma16(pk2.bv, vf[ds], acc[ns2][ds]);
      }
    }
    __syncthreads();   // Plds free for next slab
  }

  // BN stat partials: wave g fills cols g and 8+g of this block's row
  #pragma unroll
  for (int off = 32; off > 0; off >>= 1) {
    sc += __shfl_down(sc, off); scc += __shfl_down(scc, off);
  }
  if (lane == 0) { pstat[p * 16 + w] = sc; pstat[p * 16 + 8 + w] = scc; }

  // Coalesced U epilogue: stage each 16n x 768 f32 chunk in Plds (+pad),
  // then write full float4 cachelines. Fully unrolled (compile-time acc idx).
  float* Uq = (mq == 0) ? U0 : (mq == 1) ? U1 : (mq == 2) ? U2 : U3;
  float* Ust = (float*)Plds;     // 16 x 772 floats = 49408 B <= 64KB
  #pragma unroll
  for (int ns2 = 0; ns2 < 4; ++ns2) {
    #pragma unroll
    for (int ds = 0; ds < 6; ++ds)
      #pragma unroll
      for (int r = 0; r < 4; ++r)
        Ust[(lhi * 4 + r) * 772 + w * 96 + ds * 16 + l15] = acc[ns2][ds][r];
    __syncthreads();
    int nbase = ng * 64 + ns2 * 16;
    #pragma unroll
    for (int j = 0; j < 6; ++j) {
      int i4 = t + j * 512;                 // [0, 3072) float4 units
      int row = i4 / 192, c4 = i4 - row * 192;
      float4 v = *(const float4*)&Ust[row * 772 + c4 * 4];
      *(float4*)&Uq[((size_t)(b * 1024 + nbase + row)) * 768 + c4 * 4] = v;
    }
    __syncthreads();
  }
}

// ------------------------------------------------- colsum(V) per (b,h,d), fp32
__global__ __launch_bounds__(384) void k_vcs(const float* __restrict__ vb,
                                             float* __restrict__ vcs)
{
  __shared__ float part[4][96];
  int bh = blockIdx.x, t = threadIdx.x;
  int c = t % 96, g4 = t / 96;
  float a = 0.f;
  const float* vp = vb + (size_t)bh * 98304 + (size_t)g4 * 24576 + c;
  for (int m = 0; m < 256; ++m) a += vp[m * 96];
  part[g4][c] = a;
  __syncthreads();
  if (t < 96) vcs[bh * 96 + t] = part[0][t] + part[1][t] + part[2][t] + part[3][t];
}

// ---------------- BN partial reduce: 256 rows x 16 -> stats[16]
__global__ __launch_bounds__(256) void k_statred(const float* __restrict__ pstat,
                                                 float* __restrict__ stats)
{
  __shared__ float part[16][17];
  int t = threadIdx.x;
  int j = t >> 4, s = t & 15;
  float a = 0.f;
  #pragma unroll
  for (int k2 = 0; k2 < 16; ++k2)
    a += pstat[(size_t)(s + 16 * k2) * 16 + j];
  part[j][s] = a;
  __syncthreads();
  if (t < 16) {
    float v = 0.f;
    #pragma unroll
    for (int s2 = 0; s2 < 16; ++s2) v += part[t][s2];
    stats[t] = v;
  }
}

// ------------- BN affine: ubb = bf16(sg*(U0+U1+U2+U3) + (bnb - sg*mc)*colsum(V))
__global__ __launch_bounds__(256) void k_bnfin(const float* __restrict__ U0,
    const float* __restrict__ U1, const float* __restrict__ U2,
    const float* __restrict__ U3, const float* __restrict__ vcs,
    const float* __restrict__ stats, const float* __restrict__ bng,
    const float* __restrict__ bnb, u16* __restrict__ ubb)
{
  size_t idx = (size_t)blockIdx.x * 256 + threadIdx.x;
  int col = (int)(idx % 768); int i = (int)(idx / 768); int b = i >> 10;
  int g = col / 96, d = col - g * 96;
  const float cnt = 4194304.f;  // B*N*N
  float mc = stats[g] / cnt;
  float var = stats[8 + g] / cnt - mc * mc;
  float sg = bng[g] * rsqrtf(var + EPSV);
  float tg = bnb[g] - sg * mc;
  float u = (U0[idx] + U1[idx]) + (U2[idx] + U3[idx]);
  ubb[idx] = f2bf(sg * u + tg * vcs[(b * 8 + g) * 96 + d]);
}

// -------- bf16 MFMA GEMM: out = A[M,K]@W[N,K]^T + bias (+res)(+gelu)(+LN stats)
template<int GELU_, int RES_, int STATS_, int BF16OUT>
__global__ __launch_bounds__(256) void k_gemm(
    const u16* __restrict__ A, const u16* __restrict__ W,
    const float* __restrict__ bias, const float* __restrict__ res,
    float* __restrict__ out, u16* __restrict__ outb,
    int K, int Nc, float* __restrict__ stats)
{
  __shared__ u16 As[8192], Bs[8192];   // 128 rows x 64 cols, XOR-swizzled
  __shared__ float red[8];
  int t = threadIdx.x, lane = t & 63, wv = t >> 6;
  int l15 = lane & 15, lhi = lane >> 4;
  int i0 = blockIdx.y * 128, j0 = blockIdx.x * 128;
  int wr = wv >> 1, wc = wv & 1;
  f32x4 acc[4][4];
  #pragma unroll
  for (int mi = 0; mi < 4; ++mi)
    #pragma unroll
    for (int ni = 0; ni < 4; ++ni) acc[mi][ni] = (f32x4){0.f, 0.f, 0.f, 0.f};
  int rA = lane >> 3;
  int colel = 8 * ((lane & 7) ^ rA);   // pre-swizzled global source column
  for (int k0 = 0; k0 < K; k0 += 64) {
    if (k0) __syncthreads();
    #pragma unroll
    for (int i = 0; i < 4; ++i) {
      int cA = wv * 4 + i;
      int r = cA * 8 + rA;
      gload16(A + (size_t)(i0 + r) * K + k0 + colel, &As[cA * 512]);
      gload16(W + (size_t)(j0 + r) * K + k0 + colel, &Bs[cA * 512]);
    }
    __syncthreads();
    #pragma unroll
    for (int ks = 0; ks < 2; ++ks) {
      bf16x8 af[4], bf[4];
      #pragma unroll
      for (int mi = 0; mi < 4; ++mi) {
        int r2 = wr * 64 + mi * 16 + l15;
        af[mi] = *(const bf16x8*)&As[r2 * 64 + ((ks * 32 + lhi * 8) ^ (8 * (r2 & 7)))];
      }
      #pragma unroll
      for (int ni = 0; ni < 4; ++ni) {
        int r3 = wc * 64 + ni * 16 + l15;
        bf[ni] = *(const bf16x8*)&Bs[r3 * 64 + ((ks * 32 + lhi * 8) ^ (8 * (r3 & 7)))];
      }
      #pragma unroll
      for (int mi = 0; mi < 4; ++mi)
        #pragma unroll
        for (int ni = 0; ni < 4; ++ni)
          acc[mi][ni] = mfma16(af[mi], bf[ni], acc[mi][ni]);
    }
  }
  float ls = 0.f, lss = 0.f;
  #pragma unroll
  for (int mi = 0; mi < 4; ++mi) {
    #pragma unroll
    for (int ni = 0; ni < 4; ++ni) {
      int col = j0 + wc * 64 + ni * 16 + l15;
      float bv = bias[col];
      #pragma unroll
      for (int r = 0; r < 4; ++r) {
        int row = i0 + wr * 64 + mi * 16 + lhi * 4 + r;
        float val = acc[mi][ni][r] + bv;
        if (RES_) val += res[(size_t)row * Nc + col];
        if (GELU_) val = 0.5f * val * (1.f + erff(val * 0.70710678118654752f));
        if (BF16OUT) outb[(size_t)row * Nc + col] = f2bf(val);
        else out[(size_t)row * Nc + col] = val;
        if (STATS_) { ls += val; lss += val * val; }
      }
    }
  }
  if (STATS_) {
    #pragma unroll
    for (int off = 32; off > 0; off >>= 1) {
      ls += __shfl_down(ls, off); lss += __shfl_down(lss, off);
    }
    if (lane == 0) { red[wv * 2] = ls; red[wv * 2 + 1] = lss; }
    __syncthreads();
    if (t == 0) {
      int b = i0 >> 10;
      atomicAdd(&stats[b * 2],     red[0] + red[2] + red[4] + red[6]);
      atomicAdd(&stats[b * 2 + 1], red[1] + red[3] + red[5] + red[7]);
    }
  }
}

// ------------------------------- joint (N,D) LayerNorm apply (per-b scalars)
template<int BF16OUT>
__global__ __launch_bounds__(256) void k_ln(const float* __restrict__ y,
    const float* __restrict__ stats, const float* __restrict__ g,
    const float* __restrict__ bta, float* __restrict__ outp, u16* __restrict__ outb)
{
  size_t idx = (size_t)blockIdx.x * 256 + threadIdx.x;
  int i = (int)(idx / 768), col = (int)(idx % 768);
  int b = i >> 10, n = i & 1023;
  const float cnt = 786432.f;  // N*D
  float mu = stats[b * 2] / cnt;
  float var = stats[b * 2 + 1] / cnt - mu * mu;
  float r = rsqrtf(var + EPSV);
  size_t gi = (size_t)n * 768 + col;
  float v = (y[idx] - mu) * r * g[gi] + bta[gi];
  outp[idx] = v;
  if (BF16OUT) outb[idx] = f2bf(v);
}

extern "C" void kernel_launch(void* const* d_in, const int* in_sizes, int n_in,
                              void* d_out, int out_size, void* d_ws, size_t ws_size,
                              hipStream_t stream)
{
  const float* x   = (const float*)d_in[0];
  const float* qw  = (const float*)d_in[1];
  const float* kw  = (const float*)d_in[2];
  const float* vw  = (const float*)d_in[3];
  const float* rw  = (const float*)d_in[4];
  const float* bng = (const float*)d_in[6];
  const float* bnb = (const float*)d_in[7];
  const float* pw  = (const float*)d_in[8];
  const float* pb  = (const float*)d_in[9];
  const float* lng = (const float*)d_in[10];
  const float* lnb = (const float*)d_in[11];
  const float* fw1 = (const float*)d_in[12];
  const float* fb1 = (const float*)d_in[13];
  const float* fw2 = (const float*)d_in[14];
  const float* fb2 = (const float*)d_in[15];
  float* out = (float*)d_out;

  float* ws    = (float*)d_ws;
  float* stats = ws;                  // 64 ([0..15] BN, [16..23] LN1, [24..31] LN2)
  float* pstat = ws + 64;             // 4096 (256 blocks x 16)
  float* vcs   = ws + 4160;           // 3072
  float* zp    = ws + 7232;           // 524288 (32 bh x 16 slots x 1024 n)
  float* invZ  = ws + 531520;         // 32768
  float* vb    = ws + 564288;         // 3145728
  float* U0    = ws + 3710016;        // 3145728
  float* U1    = ws + 6855744;        // 3145728
  float* x1    = ws + 10001472;       // 3145728
  u16* u16b = (u16*)(ws + 13147200);
  u16* qhi  = u16b;
  u16* qlo  = u16b + 3145728;
  u16* khi  = u16b + 6291456;
  u16* klo  = u16b + 9437184;
  u16* vtr  = u16b + 12582912;
  u16* ubb  = u16b + 15728640;
  u16* pwb  = u16b + 18874368;
  u16* fw1b = u16b + 19464192;
  u16* fw2b = u16b + 21823488;        // ends 24182784 u16 (~101 MB total)
  float* U2 = vb;                     // vb dead after k_vtr/k_vcs
  float* U3 = x1;                     // x1 written only later by k_ln
  u16* x1b = qhi;                     // attention u16 dead after k_attn2
  u16* hb  = qlo;                     // spans qlo..vtr
  float* y1 = U0;
  float* y2 = vb;

  hipMemsetAsync(stats, 0, 64 * sizeof(float), stream);
  k_f2b<<<1024, 256, 0, stream>>>(pw, pwb, 589824);
  k_f2b<<<2048, 256, 0, stream>>>(fw1, fw1b, 2359296);
  k_f2b<<<2048, 256, 0, stream>>>(fw2, fw2b, 2359296);

  k_conv<<<4096, 256, 0, stream>>>(x, qw, kw, vw, qhi, qlo, khi, klo, vb);
  k_vtr<<<256, 256, 0, stream>>>(vb, vtr);
  k_vcs<<<32, 384, 0, stream>>>(vb, vcs);
  k_zpass<<<512, 512, 0, stream>>>(qhi, qlo, khi, klo, zp);
  k_zmerge<<<128, 256, 0, stream>>>(zp, invZ);
  k_attn2<<<256, 512, 0, stream>>>(qhi, qlo, khi, klo, vtr, invZ, rw,
                                   U0, U1, U2, U3, pstat);
  k_statred<<<1, 256, 0, stream>>>(pstat, stats);
  k_bnfin<<<12288, 256, 0, stream>>>(U0, U1, U2, U3, vcs, stats, bng, bnb, ubb);

  k_gemm<0,1,1,0><<<dim3(6, 32), 256, 0, stream>>>(ubb, pwb, pb, x, y1, nullptr, 768, 768, stats + 16);
  k_ln<1><<<12288, 256, 0, stream>>>(y1, stats + 16, lng, lnb, x1, x1b);
  k_gemm<1,0,0,1><<<dim3(24, 32), 256, 0, stream>>>(x1b, fw1b, fb1, nullptr, nullptr, hb, 768, 3072, nullptr);
  k_gemm<0,1,1,0><<<dim3(6, 32), 256, 0, stream>>>(hb, fw2b, fb2, x1, y2, nullptr, 3072, 768, stats + 24);
  k_ln<0><<<12288, 256, 0, stream>>>(y2, stats + 24, lng, lnb, out, nullptr);
}

// Round 13
// 299.529 us; speedup vs baseline: 1.2488x; 1.1509x over previous
//
#include <hip/hip_runtime.h>
#include <math.h>

// ViT encoder block (DeepViT ReAttention), B=4 N=1024 D=768 H=8 hd=96 Hdim=3072
// R13: R12 with the hb type fixed (u16, bf16 GEMM intermediate). Scores
// computed ONCE in k_score (z partials + unnormalized P~ in PV-A-frag layout);
// k_mixpv streams P~ via global_load_lds dbuf, lane-local mix, BN stats, PV.

typedef unsigned short u16;
typedef unsigned int u32;
typedef __bf16 bf16x8 __attribute__((ext_vector_type(8)));
typedef float f32x4 __attribute__((ext_vector_type(4)));

#define EPSV 1e-5f
#define SL2E 0.14724444620253177f   // 96^-0.5 * log2(e), folded into q at conv
#define EXPC -11.541560327111707f   // -8 * log2(e)

__device__ __forceinline__ u16 f2bf(float f) {
  union { float f; u32 u; } v; v.f = f;
  u32 u = v.u + 0x7fffu + ((v.u >> 16) & 1u);
  return (u16)(u >> 16);
}
__device__ __forceinline__ float bf2f(u16 h) {
  union { u32 u; float f; } v; v.u = ((u32)h) << 16; return v.f;
}
__device__ __forceinline__ f32x4 mfma16(bf16x8 a, bf16x8 b, f32x4 c) {
  return __builtin_amdgcn_mfma_f32_16x16x32_bf16(a, b, c, 0, 0, 0);
}
__device__ __forceinline__ void gload16(const void* gp, void* lp) {
  __builtin_amdgcn_global_load_lds(
      (const __attribute__((address_space(1))) u32*)gp,
      (__attribute__((address_space(3))) u32*)lp, 16, 0, 0);
}

// ---- K staging: LINEAR LDS dest (granule G = j*512 + w*64 + lane), source
// address carries the layout permutation (inverse of the frag-native map).
struct KS { int off[3]; int hl[3]; };
__device__ __forceinline__ KS ks_init(int t) {
  KS ks;
  int lane = t & 63;
  int lh = lane >> 4, l15 = lane & 15;
  #pragma unroll
  for (int j = 0; j < 3; ++j) {
    int G = j * 512 + t;                 // granule in [0,1536)
    int hl = (G >= 768) ? 1 : 0;         // 0 = khi half, 1 = klo half
    int C = (G - hl * 768) >> 6;         // uniform per (j,wave)
    int chunk = C / 6, r = C - 6 * chunk;
    int kk = r >> 1, c1 = r & 1;
    int m = chunk * 32 + ((l15 >> 2) << 3) + (c1 << 2) + (l15 & 3);
    ks.off[j] = m * 96 + kk * 32 + lh * 8;
    ks.hl[j] = hl;
  }
  return ks;
}
__device__ __forceinline__ void ks_stage(const u16* __restrict__ khi,
    const u16* __restrict__ klo, size_t rowel, const KS& ks, u16* Kb, int t) {
  int w = t >> 6;
  #pragma unroll
  for (int j = 0; j < 3; ++j) {
    const u16* src = (ks.hl[j] ? klo : khi) + rowel + ks.off[j];
    gload16(src, Kb + (size_t)(j * 512 + w * 64) * 8);
  }
}

__device__ __forceinline__ void qload(const u16* __restrict__ qhi,
    const u16* __restrict__ qlo, size_t qoff, bf16x8* qh, bf16x8* ql) {
  #pragma unroll
  for (int kk = 0; kk < 3; ++kk) {
    qh[kk] = *(const bf16x8*)(qhi + qoff + kk * 32);
    ql[kk] = *(const bf16x8*)(qlo + qoff + kk * 32);
  }
}

// 18-MFMA split-bf16 score pair for one 32m chunk (mh) from staged LDS K.
__device__ __forceinline__ void score18(const u16* Kb, int mh, int lane,
    const bf16x8* qh, const bf16x8* ql, f32x4& C0, f32x4& C1) {
  C0 = (f32x4){0.f, 0.f, 0.f, 0.f};
  C1 = (f32x4){0.f, 0.f, 0.f, 0.f};
  #pragma unroll
  for (int kk = 0; kk < 3; ++kk) {
    const u16* base = Kb + (mh * 6 + kk * 2) * 512 + lane * 8;
    bf16x8 kh0 = *(const bf16x8*)(base);
    bf16x8 kh1 = *(const bf16x8*)(base + 512);
    bf16x8 kl0 = *(const bf16x8*)(base + 6144);
    bf16x8 kl1 = *(const bf16x8*)(base + 6656);
    C0 = mfma16(kh0, qh[kk], C0);
    C0 = mfma16(kl0, qh[kk], C0);
    C0 = mfma16(kh0, ql[kk], C0);
    C1 = mfma16(kh1, qh[kk], C1);
    C1 = mfma16(kl1, qh[kk], C1);
    C1 = mfma16(kh1, ql[kk], C1);
  }
}

// ---------------------------------------------------------------- fp32 -> bf16
__global__ __launch_bounds__(256) void k_f2b(const float* __restrict__ s,
                                             u16* __restrict__ d, int n) {
  int i = blockIdx.x * 256 + threadIdx.x;
  int stride = gridDim.x * 256;
  for (; i < n; i += stride) d[i] = f2bf(s[i]);
}

// ---------------------------------------------------------------- conv 3x3 QKV
__global__ __launch_bounds__(256) void k_conv(const float* __restrict__ x,
    const float* __restrict__ wq, const float* __restrict__ wk, const float* __restrict__ wv,
    u16* __restrict__ qhi, u16* __restrict__ qlo,
    u16* __restrict__ khi, u16* __restrict__ klo,
    float* __restrict__ vb)
{
  __shared__ float patch[768], swq[81], swk[81], swv[81];
  int bid = blockIdx.x;            // b*1024 + n
  int b = bid >> 10, n = bid & 1023;
  int t = threadIdx.x;
  const float* xr = x + (size_t)bid * 768;
  patch[t] = xr[t]; patch[t + 256] = xr[t + 256]; patch[t + 512] = xr[t + 512];
  if (t < 81) { swq[t] = wq[t]; swk[t] = wk[t]; swv[t] = wv[t]; }
  __syncthreads();
  #pragma unroll
  for (int r = 0; r < 3; ++r) {
    int f = t + 256 * r;                       // c*256 + p*16 + q
    int o = f >> 8, rem = f & 255, pp = rem >> 4, qq = rem & 15;
    float aq = 0.f, ak = 0.f, av = 0.f;
    #pragma unroll
    for (int i = 0; i < 3; ++i)
      #pragma unroll
      for (int dp = 0; dp < 3; ++dp) {
        int ip = pp + dp - 1;
        if (ip < 0 || ip > 15) continue;
        #pragma unroll
        for (int dq = 0; dq < 3; ++dq) {
          int iq = qq + dq - 1;
          if (iq < 0 || iq > 15) continue;
          float pv = patch[i * 256 + ip * 16 + iq];
          int wi = ((o * 3 + i) * 3 + dp) * 3 + dq;
          aq += swq[wi] * pv; ak += swk[wi] * pv; av += swv[wi] * pv;
        }
      }
    int h = f / 96, d = f - h * 96;
    size_t oi = ((size_t)(b * 8 + h) * 1024 + n) * 96 + d;
    float aqs = aq * SL2E;           // fold softmax scale + log2e into q
    u16 qh_ = f2bf(aqs); qhi[oi] = qh_; qlo[oi] = f2bf(aqs - bf2f(qh_));
    u16 kh_ = f2bf(ak);  khi[oi] = kh_; klo[oi] = f2bf(ak - bf2f(kh_));
    vb[oi] = av;
  }
}

// ------------------------------- V transpose: [bh][n][d] f32 -> [bh][d][n] bf16
__global__ __launch_bounds__(256) void k_vtr(const float* __restrict__ vb,
                                             u16* __restrict__ vtr)
{
  __shared__ u16 lds[12288];     // [96 d][128 n]
  int bid = blockIdx.x;          // bh*8 + ntile
  int bh = bid >> 3, n0 = (bid & 7) * 128;
  int t = threadIdx.x;
  int n = t >> 1, dh = (t & 1) * 48;
  const float* src = vb + ((size_t)bh * 1024 + n0 + n) * 96 + dh;
  #pragma unroll
  for (int j4 = 0; j4 < 12; ++j4) {
    float4 v = *(const float4*)(src + j4 * 4);
    int d = dh + j4 * 4;
    lds[(d + 0) * 128 + n] = f2bf(v.x);
    lds[(d + 1) * 128 + n] = f2bf(v.y);
    lds[(d + 2) * 128 + n] = f2bf(v.z);
    lds[(d + 3) * 128 + n] = f2bf(v.w);
  }
  __syncthreads();
  #pragma unroll
  for (int j = 0; j < 48; ++j) {
    int flat = t + 256 * j;
    int d = flat >> 7, n2 = flat & 127;
    vtr[((size_t)bh * 96 + d) * 1024 + n0 + n2] = lds[flat];
  }
}

// -------- score pass: z partials AND unnormalized P~ frags (PV-A-frag layout)
// pt index: ((((b*8+h)*32 + mc)*64 + nt)*64 + lane)*8
__global__ __launch_bounds__(512, 2) void k_score(
    const u16* __restrict__ qhi, const u16* __restrict__ qlo,
    const u16* __restrict__ khi, const u16* __restrict__ klo,
    float* __restrict__ zp, u16* __restrict__ pt)
{
  __shared__ u16 Kst[2][12288];
  int p = blockIdx.x;            // 512 blocks
  int s = p >> 3;                // [0,64)
  int c = (p & 7) * 4 + (s >> 4);// [0,32) = (b,mg) combo
  int ng = s & 15;
  int b = c >> 3, mg = c & 7;
  int t = threadIdx.x, lane = t & 63, w = t >> 6;
  int l15 = lane & 15, lhi = lane >> 4;
  int nsub = w >> 1, mh = w & 1;
  int n0 = ng * 64 + nsub * 16;
  int nt = ng * 4 + nsub;
  int m0base = mg * 128;
  KS ks = ks_init(t);
  bf16x8 qh[3], ql[3], qh2[3], ql2[3];
  size_t bh0 = (size_t)(b * 8) * 1024;
  ks_stage(khi, klo, (bh0 + m0base) * 96, ks, Kst[0], t);
  qload(qhi, qlo, (bh0 + n0 + l15) * 96 + lhi * 8, qh, ql);
  __syncthreads();
  #pragma unroll 1
  for (int h = 0; h < 8; ++h) {
    float z = 0.f;
    #pragma unroll
    for (int mt = 0; mt < 2; ++mt) {
      int u = h * 2 + mt;
      if (u < 15) {   // prefetch next unit into the free buffer
        int un = u + 1, hn = un >> 1, mtn = un & 1;
        size_t bhn = (size_t)(b * 8 + hn) * 1024;
        ks_stage(khi, klo, (bhn + m0base + mtn * 64) * 96, ks, Kst[(u + 1) & 1], t);
        if (mtn == 0)
          qload(qhi, qlo, (bhn + n0 + l15) * 96 + lhi * 8, qh2, ql2);
      }
      f32x4 C0, C1;
      score18(Kst[u & 1], mh, lane, qh, ql, C0, C1);
      union { u16 us[8]; uint4 q4; } pk;
      #pragma unroll
      for (int r = 0; r < 4; ++r) {
        float e0 = exp2f(C0[r] + EXPC);
        float e1 = exp2f(C1[r] + EXPC);
        z += e0 + e1;
        pk.us[r]     = f2bf(e0);
        pk.us[4 + r] = f2bf(e1);
      }
      int mc = mg * 4 + mt * 2 + mh;     // [0,32)
      *(uint4*)&pt[((((size_t)(b * 8 + h) * 32 + mc) * 64 + nt) * 64 + lane) * 8] = pk.q4;
      if (u < 15 && mt == 1) {
        #pragma unroll
        for (int kk = 0; kk < 3; ++kk) { qh[kk] = qh2[kk]; ql[kk] = ql2[kk]; }
      }
      __syncthreads();
    }
    z += __shfl_xor(z, 16);
    z += __shfl_xor(z, 32);
    if (lane < 16)
      zp[((size_t)((b * 8 + h) * 16 + mg * 2 + mh)) * 1024 + n0 + lane] = z;
  }
}

// --------------------------------------- merge 16 z slots -> invZ
__global__ __launch_bounds__(256) void k_zmerge(const float* __restrict__ zp,
                                                float* __restrict__ invZ)
{
  int idx = blockIdx.x * 256 + threadIdx.x;   // < 32768
  int bh = idx >> 10, n = idx & 1023;
  float z = 0.f;
  #pragma unroll
  for (int s = 0; s < 16; ++s) z += zp[((size_t)(bh * 16 + s)) * 1024 + n];
  invZ[idx] = 1.f / z;
}

// -------- mix + PV: per block (b, 16n tile), full m. wave w = output head g.
__global__ __launch_bounds__(512, 2) void k_mixpv(
    const u16* __restrict__ pt, const u16* __restrict__ vtr,
    const float* __restrict__ invZ, const float* __restrict__ rw,
    float* __restrict__ U, float* __restrict__ pstat)
{
  __shared__ u16 Pst[2][8192];   // dbuf: [h 8][lane 64][8 u16] per 32m chunk
  int p = blockIdx.x;            // 256 = 4b x 64nt, XCD-swizzled
  int xcd = p & 7;
  int b = xcd >> 1, nt = (xcd & 1) * 32 + (p >> 3);
  int t = threadIdx.x, lane = t & 63, w = t >> 6;   // w = output head g
  int l15 = lane & 15, lhi = lane >> 4;

  float wg[8]; float wsum = 0.f;
  #pragma unroll
  for (int h = 0; h < 8; ++h) { wg[h] = rw[w * 8 + h]; wsum += wg[h]; }
  float cg = -wsum * (1.f / 1024.f);
  float wz[8];
  #pragma unroll
  for (int h = 0; h < 8; ++h)
    wz[h] = wg[h] * invZ[(b * 8 + h) * 1024 + nt * 16 + l15];

  f32x4 acc[6];
  #pragma unroll
  for (int ds = 0; ds < 6; ++ds) acc[ds] = (f32x4){0.f, 0.f, 0.f, 0.f};
  float sc = 0.f, scc = 0.f;
  size_t vbase = (size_t)(b * 8 + w) * 96;
  size_t pbase = ((size_t)(b * 8 + w) * 32) * 4096 + (size_t)nt * 64;  // granules

  gload16(pt + (pbase + lane) * 8, &Pst[0][(size_t)t * 8]);
  __syncthreads();
  #pragma unroll 1
  for (int mc = 0; mc < 32; ++mc) {
    if (mc < 31)
      gload16(pt + (pbase + (size_t)(mc + 1) * 4096 + lane) * 8,
              &Pst[(mc + 1) & 1][(size_t)t * 8]);
    int mof = mc * 32 + lhi * 8;
    bf16x8 vf[6];
    #pragma unroll
    for (int ds = 0; ds < 6; ++ds)
      vf[ds] = *(const bf16x8*)(vtr + (vbase + ds * 16 + l15) * 1024 + mof);
    float cm8[8];
    #pragma unroll
    for (int j = 0; j < 8; ++j) cm8[j] = cg;
    const u16* Pb = &Pst[mc & 1][0];
    #pragma unroll
    for (int h = 0; h < 8; ++h) {
      union { u32 ud[4]; bf16x8 bv; } pf;
      pf.bv = *(const bf16x8*)&Pb[(h * 64 + lane) * 8];
      float wzh = wz[h];
      #pragma unroll
      for (int k2 = 0; k2 < 4; ++k2) {
        union { u32 u; float f; } lo, hi;
        lo.u = pf.ud[k2] << 16;
        hi.u = pf.ud[k2] & 0xffff0000u;
        cm8[2 * k2]     += wzh * lo.f;
        cm8[2 * k2 + 1] += wzh * hi.f;
      }
    }
    union { u16 us[8]; bf16x8 bv; } pk2;
    #pragma unroll
    for (int j = 0; j < 8; ++j) {
      sc += cm8[j]; scc += cm8[j] * cm8[j];
      pk2.us[j] = f2bf(cm8[j]);
    }
    #pragma unroll
    for (int ds = 0; ds < 6; ++ds)
      acc[ds] = mfma16(pk2.bv, vf[ds], acc[ds]);
    __syncthreads();   // next P~ chunk staged (barrier drains vmcnt)
  }

  // BN stat partials: wave g -> cols g and 8+g of row p
  #pragma unroll
  for (int off = 32; off > 0; off >>= 1) {
    sc += __shfl_down(sc, off); scc += __shfl_down(scc, off);
  }
  if (lane == 0) { pstat[p * 16 + w] = sc; pstat[p * 16 + 8 + w] = scc; }

  #pragma unroll
  for (int ds = 0; ds < 6; ++ds)
    #pragma unroll
    for (int r = 0; r < 4; ++r) {
      int n = nt * 16 + lhi * 4 + r;
      U[((size_t)(b * 1024 + n)) * 768 + w * 96 + ds * 16 + l15] = acc[ds][r];
    }
}

// ------------------------------------------------- colsum(V) per (b,h,d), fp32
__global__ __launch_bounds__(384) void k_vcs(const float* __restrict__ vb,
                                             float* __restrict__ vcs)
{
  __shared__ float part[4][96];
  int bh = blockIdx.x, t = threadIdx.x;
  int c = t % 96, g4 = t / 96;
  float a = 0.f;
  const float* vp = vb + (size_t)bh * 98304 + (size_t)g4 * 24576 + c;
  for (int m = 0; m < 256; ++m) a += vp[m * 96];
  part[g4][c] = a;
  __syncthreads();
  if (t < 96) vcs[bh * 96 + t] = part[0][t] + part[1][t] + part[2][t] + part[3][t];
}

// ---------------- BN partial reduce: 256 rows x 16 -> stats[16]
__global__ __launch_bounds__(256) void k_statred(const float* __restrict__ pstat,
                                                 float* __restrict__ stats)
{
  __shared__ float part[16][17];
  int t = threadIdx.x;
  int j = t >> 4, s = t & 15;
  float a = 0.f;
  #pragma unroll
  for (int k2 = 0; k2 < 16; ++k2)
    a += pstat[(size_t)(s + 16 * k2) * 16 + j];
  part[j][s] = a;
  __syncthreads();
  if (t < 16) {
    float v = 0.f;
    #pragma unroll
    for (int s2 = 0; s2 < 16; ++s2) v += part[t][s2];
    stats[t] = v;
  }
}

// ------------- BN affine: ubb = bf16(sg*U + (bnb - sg*mc)*colsum(V))
__global__ __launch_bounds__(256) void k_bnfin(const float* __restrict__ U,
    const float* __restrict__ vcs, const float* __restrict__ stats,
    const float* __restrict__ bng, const float* __restrict__ bnb,
    u16* __restrict__ ubb)
{
  size_t idx = (size_t)blockIdx.x * 256 + threadIdx.x;
  int col = (int)(idx % 768); int i = (int)(idx / 768); int b = i >> 10;
  int g = col / 96, d = col - g * 96;
  const float cnt = 4194304.f;  // B*N*N
  float mc = stats[g] / cnt;
  float var = stats[8 + g] / cnt - mc * mc;
  float sg = bng[g] * rsqrtf(var + EPSV);
  float tg = bnb[g] - sg * mc;
  ubb[idx] = f2bf(sg * U[idx] + tg * vcs[(b * 8 + g) * 96 + d]);
}

// -------- bf16 MFMA GEMM: out = A[M,K]@W[N,K]^T + bias (+res)(+gelu)(+LN stats)
template<int GELU_, int RES_, int STATS_, int BF16OUT>
__global__ __launch_bounds__(256) void k_gemm(
    const u16* __restrict__ A, const u16* __restrict__ W,
    const float* __restrict__ bias, const float* __restrict__ res,
    float* __restrict__ out, u16* __restrict__ outb,
    int K, int Nc, float* __restrict__ stats)
{
  __shared__ u16 As[8192], Bs[8192];   // 128 rows x 64 cols, XOR-swizzled
  __shared__ float red[8];
  int t = threadIdx.x, lane = t & 63, wv = t >> 6;
  int l15 = lane & 15, lhi = lane >> 4;
  int i0 = blockIdx.y * 128, j0 = blockIdx.x * 128;
  int wr = wv >> 1, wc = wv & 1;
  f32x4 acc[4][4];
  #pragma unroll
  for (int mi = 0; mi < 4; ++mi)
    #pragma unroll
    for (int ni = 0; ni < 4; ++ni) acc[mi][ni] = (f32x4){0.f, 0.f, 0.f, 0.f};
  int rA = lane >> 3;
  int colel = 8 * ((lane & 7) ^ rA);   // pre-swizzled global source column
  for (int k0 = 0; k0 < K; k0 += 64) {
    if (k0) __syncthreads();
    #pragma unroll
    for (int i = 0; i < 4; ++i) {
      int cA = wv * 4 + i;
      int r = cA * 8 + rA;
      gload16(A + (size_t)(i0 + r) * K + k0 + colel, &As[cA * 512]);
      gload16(W + (size_t)(j0 + r) * K + k0 + colel, &Bs[cA * 512]);
    }
    __syncthreads();
    #pragma unroll
    for (int ks = 0; ks < 2; ++ks) {
      bf16x8 af[4], bf[4];
      #pragma unroll
      for (int mi = 0; mi < 4; ++mi) {
        int r2 = wr * 64 + mi * 16 + l15;
        af[mi] = *(const bf16x8*)&As[r2 * 64 + ((ks * 32 + lhi * 8) ^ (8 * (r2 & 7)))];
      }
      #pragma unroll
      for (int ni = 0; ni < 4; ++ni) {
        int r3 = wc * 64 + ni * 16 + l15;
        bf[ni] = *(const bf16x8*)&Bs[r3 * 64 + ((ks * 32 + lhi * 8) ^ (8 * (r3 & 7)))];
      }
      #pragma unroll
      for (int mi = 0; mi < 4; ++mi)
        #pragma unroll
        for (int ni = 0; ni < 4; ++ni)
          acc[mi][ni] = mfma16(af[mi], bf[ni], acc[mi][ni]);
    }
  }
  float ls = 0.f, lss = 0.f;
  #pragma unroll
  for (int mi = 0; mi < 4; ++mi) {
    #pragma unroll
    for (int ni = 0; ni < 4; ++ni) {
      int col = j0 + wc * 64 + ni * 16 + l15;
      float bv = bias[col];
      #pragma unroll
      for (int r = 0; r < 4; ++r) {
        int row = i0 + wr * 64 + mi * 16 + lhi * 4 + r;
        float val = acc[mi][ni][r] + bv;
        if (RES_) val += res[(size_t)row * Nc + col];
        if (GELU_) val = 0.5f * val * (1.f + erff(val * 0.70710678118654752f));
        if (BF16OUT) outb[(size_t)row * Nc + col] = f2bf(val);
        else out[(size_t)row * Nc + col] = val;
        if (STATS_) { ls += val; lss += val * val; }
      }
    }
  }
  if (STATS_) {
    #pragma unroll
    for (int off = 32; off > 0; off >>= 1) {
      ls += __shfl_down(ls, off); lss += __shfl_down(lss, off);
    }
    if (lane == 0) { red[wv * 2] = ls; red[wv * 2 + 1] = lss; }
    __syncthreads();
    if (t == 0) {
      int b = i0 >> 10;
      atomicAdd(&stats[b * 2],     red[0] + red[2] + red[4] + red[6]);
      atomicAdd(&stats[b * 2 + 1], red[1] + red[3] + red[5] + red[7]);
    }
  }
}

// ------------------------------- joint (N,D) LayerNorm apply (per-b scalars)
template<int BF16OUT>
__global__ __launch_bounds__(256) void k_ln(const float* __restrict__ y,
    const float* __restrict__ stats, const float* __restrict__ g,
    const float* __restrict__ bta, float* __restrict__ outp, u16* __restrict__ outb)
{
  size_t idx = (size_t)blockIdx.x * 256 + threadIdx.x;
  int i = (int)(idx / 768), col = (int)(idx % 768);
  int b = i >> 10, n = i & 1023;
  const float cnt = 786432.f;  // N*D
  float mu = stats[b * 2] / cnt;
  float var = stats[b * 2 + 1] / cnt - mu * mu;
  float r = rsqrtf(var + EPSV);
  size_t gi = (size_t)n * 768 + col;
  float v = (y[idx] - mu) * r * g[gi] + bta[gi];
  outp[idx] = v;
  if (BF16OUT) outb[idx] = f2bf(v);
}

extern "C" void kernel_launch(void* const* d_in, const int* in_sizes, int n_in,
                              void* d_out, int out_size, void* d_ws, size_t ws_size,
                              hipStream_t stream)
{
  const float* x   = (const float*)d_in[0];
  const float* qw  = (const float*)d_in[1];
  const float* kw  = (const float*)d_in[2];
  const float* vw  = (const float*)d_in[3];
  const float* rw  = (const float*)d_in[4];
  const float* bng = (const float*)d_in[6];
  const float* bnb = (const float*)d_in[7];
  const float* pw  = (const float*)d_in[8];
  const float* pb  = (const float*)d_in[9];
  const float* lng = (const float*)d_in[10];
  const float* lnb = (const float*)d_in[11];
  const float* fw1 = (const float*)d_in[12];
  const float* fb1 = (const float*)d_in[13];
  const float* fw2 = (const float*)d_in[14];
  const float* fb2 = (const float*)d_in[15];
  float* out = (float*)d_out;

  // ---- workspace layout (u16 units), ~111 MB total, heavy aliasing ----
  u16* pt   = (u16*)d_ws;              // 33,554,432 u16 (P~, k_score->k_mixpv)
  float* vb = (float*)pt;              // 3,145,728 f  (conv->vcs; dead before k_score)
  u16* hb   = pt;                      // 12,582,912 u16 (gemm phase; pt dead)
  float* y2 = (float*)pt + 12582912;   // 3,145,728 f  (disjoint from hb region)
  float* fsm = (float*)(pt + 33554432);
  float* stats = fsm;                  // 64
  float* pstat = fsm + 64;             // 4096
  float* vcs   = fsm + 4160;           // 3072
  float* zp    = fsm + 7232;           // 524288
  float* invZ  = fsm + 531520;         // 32768  (fsm total 564,288 f)
  u16* qhi  = (u16*)(fsm + 564288);    // 3,145,728
  u16* qlo  = qhi + 3145728;
  u16* khi  = qlo + 3145728;
  u16* klo  = khi + 3145728;
  u16* vtrb = klo + 3145728;           // vtr; then ubb; then x1b
  u16* pwb  = vtrb + 3145728;
  u16* fw1b = pwb + 589824;
  u16* fw2b = fw1b + 2359296;          // end ~111.4 MB
  float* U0 = (float*)qhi;             // after k_score (qhi/qlo dead)
  float* x1 = (float*)khi;             // after k_mixpv (khi/klo dead)
  float* y1 = U0;
  u16* ubb  = vtrb;                    // after k_mixpv (vtr dead)
  u16* x1b  = vtrb;                    // after gemm1 (ubb dead)

  hipMemsetAsync(stats, 0, 64 * sizeof(float), stream);
  k_f2b<<<1024, 256, 0, stream>>>(pw, pwb, 589824);
  k_f2b<<<2048, 256, 0, stream>>>(fw1, fw1b, 2359296);
  k_f2b<<<2048, 256, 0, stream>>>(fw2, fw2b, 2359296);

  k_conv<<<4096, 256, 0, stream>>>(x, qw, kw, vw, qhi, qlo, khi, klo, vb);
  k_vtr<<<256, 256, 0, stream>>>(vb, vtrb);
  k_vcs<<<32, 384, 0, stream>>>(vb, vcs);
  k_score<<<512, 512, 0, stream>>>(qhi, qlo, khi, klo, zp, pt);
  k_zmerge<<<128, 256, 0, stream>>>(zp, invZ);
  k_mixpv<<<256, 512, 0, stream>>>(pt, vtrb, invZ, rw, U0, pstat);
  k_statred<<<1, 256, 0, stream>>>(pstat, stats);
  k_bnfin<<<12288, 256, 0, stream>>>(U0, vcs, stats, bng, bnb, ubb);

  k_gemm<0,1,1,0><<<dim3(6, 32), 256, 0, stream>>>(ubb, pwb, pb, x, y1, nullptr, 768, 768, stats + 16);
  k_ln<1><<<12288, 256, 0, stream>>>(y1, stats + 16, lng, lnb, x1, x1b);
  k_gemm<1,0,0,1><<<dim3(24, 32), 256, 0, stream>>>(x1b, fw1b, fb1, nullptr, nullptr, hb, 768, 3072, nullptr);
  k_gemm<0,1,1,0><<<dim3(6, 32), 256, 0, stream>>>(hb, fw2b, fb2, x1, y2, nullptr, 3072, 768, stats + 24);
  k_ln<0><<<12288, 256, 0, stream>>>(y2, stats + 24, lng, lnb, out, nullptr);
}